// Round 1
// baseline (601.180 us; speedup 1.0000x reference)
//
#include <hip/hip_runtime.h>
#include <hip/hip_bf16.h>
#include <stdint.h>

// Problem constants (FlaxGPTNeoSelfAttention): B=2, S=2048, D=2048, H=16, HD=128
#define Bv 2
#define Sv 2048
#define Dv 2048
#define Hv 16
#define HDv 128
#define Mv (Bv*Sv)   // 4096 rows for the projection GEMMs

typedef __attribute__((ext_vector_type(8))) short short8;
typedef __attribute__((ext_vector_type(4))) short short4v;
typedef __attribute__((ext_vector_type(4))) float f32x4;

__device__ __forceinline__ unsigned short bf16_rne(float f) {
    union { float f; uint32_t u; } c; c.f = f;
    uint32_t u = c.u;
    u += 0x7fffu + ((u >> 16) & 1u);   // round-to-nearest-even (inputs are finite randoms)
    return (unsigned short)(u >> 16);
}

__device__ __forceinline__ void gload16(const void* g, void* l) {
    // async global->LDS, 16B per lane; LDS dest = wave-uniform base + lane*16
    __builtin_amdgcn_global_load_lds((const __attribute__((address_space(1))) void*)g,
                                     (__attribute__((address_space(3))) void*)l, 16, 0, 0);
}

// ---------------- kernel 1: hidden_states fp32 -> bf16 ----------------
__global__ void cvt_x_kernel(const float* __restrict__ x, unsigned short* __restrict__ xb) {
    int i = (blockIdx.x * 256 + threadIdx.x) * 4;
    float4 v = *(const float4*)(x + i);
    short4v o;
    o[0] = (short)bf16_rne(v.x);
    o[1] = (short)bf16_rne(v.y);
    o[2] = (short)bf16_rne(v.z);
    o[3] = (short)bf16_rne(v.w);
    *(short4v*)(xb + i) = o;
}

// ---------------- kernel 2: weights fp32 -> bf16, transposed Wt[n][k] ----------------
__global__ void cvt_wt_kernel(const float* __restrict__ w0, const float* __restrict__ w1,
                              const float* __restrict__ w2, const float* __restrict__ w3,
                              unsigned short* __restrict__ wt) {
    __shared__ unsigned short t[64][65];
    int z = blockIdx.z;
    const float* w = (z == 0) ? w0 : (z == 1) ? w1 : (z == 2) ? w2 : w3;
    unsigned short* o = wt + (size_t)z * Dv * Dv;
    int k0 = blockIdx.x * 64, n0 = blockIdx.y * 64;
    for (int i = threadIdx.x; i < 4096; i += 256) {
        int r = i >> 6, c = i & 63;
        t[r][c] = bf16_rne(w[(size_t)(k0 + r) * Dv + n0 + c]);
    }
    __syncthreads();
    for (int i = threadIdx.x; i < 4096; i += 256) {
        int r = i >> 6, c = i & 63;
        o[(size_t)(n0 + r) * Dv + k0 + c] = t[c][r];
    }
}

// ---------------- kernel 3/5: GEMM  C[M][N] = A[M][K] @ Wt[N][K]^T ----------------
// 128x128 tile, BK=32, 4 waves (2x2), 16x16x32 bf16 MFMA.
// FOUT=0: bf16 store to CbBase (+z offsets). FOUT=1: fp32 store to Cf with +bias.
template<int FOUT>
__global__ __launch_bounds__(256) void gemm_bt_kernel(
    const unsigned short* __restrict__ A,
    const unsigned short* __restrict__ WtBase,
    unsigned short* __restrict__ CbBase,
    float* __restrict__ Cf,
    const float* __restrict__ bias)
{
    __shared__ unsigned short lA[128 * 32];
    __shared__ unsigned short lB[128 * 32];
    const int tid = threadIdx.x;
    const int wv = tid >> 6, ln = tid & 63;
    const int lr = ln & 15, lg = ln >> 4;
    const int wm = wv >> 1, wn = wv & 1;
    const int m0 = blockIdx.x * 128, n0 = blockIdx.y * 128;
    const int z = blockIdx.z;
    const unsigned short* Wt = WtBase + (size_t)z * Dv * Dv;
    unsigned short* Cb = CbBase + (size_t)z * (size_t)Mv * Dv;

    const int srow = tid >> 2;        // 0..63: row covered by this thread's 16B chunk
    const int scol = (tid & 3) * 8;   // k element offset of the chunk

    f32x4 acc[4][4];
    #pragma unroll
    for (int m = 0; m < 4; m++)
        #pragma unroll
        for (int n = 0; n < 4; n++)
            acc[m][n] = (f32x4){0.f, 0.f, 0.f, 0.f};

    for (int kt = 0; kt < Dv; kt += 32) {
        // stage A[128][32] and B(Wt)[128][32] linearly (dest = wave base + lane*16)
        gload16(A  + (size_t)(m0 +      srow) * Dv + kt + scol, &lA[wv * 512]);
        gload16(A  + (size_t)(m0 + 64 + srow) * Dv + kt + scol, &lA[2048 + wv * 512]);
        gload16(Wt + (size_t)(n0 +      srow) * Dv + kt + scol, &lB[wv * 512]);
        gload16(Wt + (size_t)(n0 + 64 + srow) * Dv + kt + scol, &lB[2048 + wv * 512]);
        __syncthreads();   // drains vmcnt before barrier

        short8 af[4], bfv[4];
        #pragma unroll
        for (int m = 0; m < 4; m++)
            af[m] = *(const short8*)&lA[(wm * 64 + m * 16 + lr) * 32 + lg * 8];
        #pragma unroll
        for (int n = 0; n < 4; n++)
            bfv[n] = *(const short8*)&lB[(wn * 64 + n * 16 + lr) * 32 + lg * 8];
        #pragma unroll
        for (int m = 0; m < 4; m++)
            #pragma unroll
            for (int n = 0; n < 4; n++)
                acc[m][n] = __builtin_amdgcn_mfma_f32_16x16x32_bf16(af[m], bfv[n], acc[m][n], 0, 0, 0);
        __syncthreads();
    }

    // epilogue: C layout row=(l>>4)*4+r, col=l&15
    #pragma unroll
    for (int m = 0; m < 4; m++) {
        #pragma unroll
        for (int n = 0; n < 4; n++) {
            int row = m0 + wm * 64 + m * 16 + lg * 4;
            int col = n0 + wn * 64 + n * 16 + lr;
            #pragma unroll
            for (int r = 0; r < 4; r++) {
                if (FOUT)
                    Cf[(size_t)(row + r) * Dv + col] = acc[m][n][r] + bias[col];
                else
                    Cb[(size_t)(row + r) * Dv + col] = bf16_rne(acc[m][n][r]);
            }
        }
    }
}

// ---------------- kernel 4: causal flash attention ----------------
// Block = 256 thr (4 waves); each block: one (b,h), 64 q-rows (16/wave). KVBLK=32.
__global__ __launch_bounds__(256) void attn_kernel(
    const unsigned short* __restrict__ Q, const unsigned short* __restrict__ K,
    const unsigned short* __restrict__ V, const int* __restrict__ pmask,
    unsigned short* __restrict__ CTX)
{
    __shared__ unsigned short lK[32 * 128];     // K tile, XOR-swizzled chunks
    __shared__ unsigned short lV[128 * 40];     // V^T tile, rows padded to 40 shorts (80B)
    __shared__ unsigned short lP[4][16 * 40];   // per-wave P tile, 80B row stride

    const int tid = threadIdx.x, wv = tid >> 6, ln = tid & 63;
    const int lr = ln & 15, lg = ln >> 4;
    const int bh = blockIdx.y;
    const int b = bh >> 4, h = bh & 15;
    const int q0 = blockIdx.x * 64;
    const int qw0 = q0 + wv * 16;
    const size_t hoff = (size_t)b * Sv * Dv + (size_t)h * HDv;

    // Q fragments for the wave's 16 rows (A-operand, 4 k-steps over HD=128)
    short8 qf[4];
    #pragma unroll
    for (int ds = 0; ds < 4; ds++)
        qf[ds] = *(const short8*)&Q[hoff + (size_t)(qw0 + lr) * Dv + ds * 32 + lg * 8];

    f32x4 acc[8];
    #pragma unroll
    for (int n = 0; n < 8; n++) acc[n] = (f32x4){0.f, 0.f, 0.f, 0.f};
    float mrow[4], lrow[4];
    #pragma unroll
    for (int r = 0; r < 4; r++) { mrow[r] = -3.0e38f; lrow[r] = 0.f; }

    const float CS = 0.12751744f;  // (1/sqrt(128)) * log2(e)
    const int nt = (q0 + 64) >> 5; // causal: kv tiles 0 .. (q0+63)/32

    for (int t = 0; t < nt; ++t) {
        const int kv0 = t << 5;
        // stage K (swizzled) and V^T (scalar transpose writes)
        #pragma unroll
        for (int ii = 0; ii < 2; ++ii) {
            int i = tid + ii * 256;
            int row = i >> 4, ch = i & 15;
            const size_t gsrc = hoff + (size_t)(kv0 + row) * Dv + ch * 8;
            short8 kvv = *(const short8*)&K[gsrc];
            *(short8*)&lK[row * 128 + ((ch ^ (row & 7)) << 3)] = kvv;
            short8 vvv = *(const short8*)&V[gsrc];
            #pragma unroll
            for (int j = 0; j < 8; j++)
                lV[(ch * 8 + j) * 40 + row] = (unsigned short)vvv[j];
        }
        __syncthreads();

        // S = Q @ K^T  (two 16-col tiles)
        f32x4 sc[2];
        #pragma unroll
        for (int ct = 0; ct < 2; ++ct) {
            f32x4 s = (f32x4){0.f, 0.f, 0.f, 0.f};
            #pragma unroll
            for (int ds = 0; ds < 4; ++ds) {
                int krow = ct * 16 + lr;
                int ch = ds * 4 + lg;
                short8 bk = *(const short8*)&lK[krow * 128 + ((ch ^ (krow & 7)) << 3)];
                s = __builtin_amdgcn_mfma_f32_16x16x32_bf16(qf[ds], bk, s, 0, 0, 0);
            }
            sc[ct] = s;
        }

        // scale + causal/pad mask (exp2 domain)
        float tv[2][4];
        #pragma unroll
        for (int ct = 0; ct < 2; ++ct) {
            int col = kv0 + ct * 16 + lr;
            bool colok = (pmask[b * Sv + col] != 0);
            #pragma unroll
            for (int r = 0; r < 4; r++) {
                int rowg = qw0 + lg * 4 + r;
                tv[ct][r] = (colok && col <= rowg) ? sc[ct][r] * CS : -1.0e30f;
            }
        }

        // online softmax: row spread across 16 lanes (lanes sharing lg)
        float rmax[4], psum[4], alpha[4];
        #pragma unroll
        for (int r = 0; r < 4; r++) rmax[r] = fmaxf(tv[0][r], tv[1][r]);
        #pragma unroll
        for (int off = 1; off < 16; off <<= 1)
            #pragma unroll
            for (int r = 0; r < 4; r++)
                rmax[r] = fmaxf(rmax[r], __shfl_xor(rmax[r], off, 64));
        #pragma unroll
        for (int r = 0; r < 4; r++) {
            float mn = fmaxf(mrow[r], rmax[r]);
            alpha[r] = exp2f(mrow[r] - mn);
            mrow[r] = mn;
        }
        #pragma unroll
        for (int r = 0; r < 4; r++) {
            float p0 = exp2f(tv[0][r] - mrow[r]);
            float p1 = exp2f(tv[1][r] - mrow[r]);
            lP[wv][(lg * 4 + r) * 40 + lr]      = bf16_rne(p0);
            lP[wv][(lg * 4 + r) * 40 + 16 + lr] = bf16_rne(p1);
            psum[r] = p0 + p1;
        }
        #pragma unroll
        for (int off = 1; off < 16; off <<= 1)
            #pragma unroll
            for (int r = 0; r < 4; r++)
                psum[r] += __shfl_xor(psum[r], off, 64);
        #pragma unroll
        for (int r = 0; r < 4; r++) lrow[r] = lrow[r] * alpha[r] + psum[r];
        #pragma unroll
        for (int n = 0; n < 8; n++)
            #pragma unroll
            for (int r = 0; r < 4; r++) acc[n][r] *= alpha[r];

        // PV: ctx += P @ V   (P from per-wave LDS, V^T from LDS)
        short8 ap = *(const short8*)&lP[wv][lr * 40 + lg * 8];
        #pragma unroll
        for (int n = 0; n < 8; n++) {
            short8 bv = *(const short8*)&lV[(n * 16 + lr) * 40 + lg * 8];
            acc[n] = __builtin_amdgcn_mfma_f32_16x16x32_bf16(ap, bv, acc[n], 0, 0, 0);
        }
        __syncthreads();
    }

    // epilogue: ctx = acc / l, bf16 store to [B,S,H,HD]
    #pragma unroll
    for (int n = 0; n < 8; n++) {
        #pragma unroll
        for (int r = 0; r < 4; r++) {
            int rowg = qw0 + lg * 4 + r;
            CTX[hoff + (size_t)rowg * Dv + n * 16 + lr] = bf16_rne(acc[n][r] / lrow[r]);
        }
    }
}

// ---------------- launcher ----------------
extern "C" void kernel_launch(void* const* d_in, const int* in_sizes, int n_in,
                              void* d_out, int out_size, void* d_ws, size_t ws_size,
                              hipStream_t stream) {
    const float* hs  = (const float*)d_in[0];
    const int*   am  = (const int*)d_in[1];
    const float* wq  = (const float*)d_in[2];
    const float* wk  = (const float*)d_in[3];
    const float* wv_ = (const float*)d_in[4];
    const float* wo  = (const float*)d_in[5];
    const float* bo  = (const float*)d_in[6];
    float* out = (float*)d_out;

    char* ws = (char*)d_ws;
    unsigned short* Xb  = (unsigned short*)ws;                               // 16 MiB: X bf16 [4096][2048]
    unsigned short* Wt  = (unsigned short*)(ws + (size_t)16 * 1024 * 1024);  // 32 MiB: 4x Wt bf16 [2048][2048]
    unsigned short* QKV = (unsigned short*)(ws + (size_t)48 * 1024 * 1024);  // 48 MiB: Q,K,V bf16
    unsigned short* CTX = (unsigned short*)(ws + (size_t)96 * 1024 * 1024);  // 16 MiB: ctx bf16

    hipLaunchKernelGGL(cvt_x_kernel, dim3(Mv * Dv / 4 / 256), dim3(256), 0, stream, hs, Xb);
    hipLaunchKernelGGL(cvt_wt_kernel, dim3(32, 32, 4), dim3(256), 0, stream, wq, wk, wv_, wo, Wt);
    hipLaunchKernelGGL(gemm_bt_kernel<0>, dim3(32, 16, 3), dim3(256), 0, stream,
                       Xb, Wt, QKV, (float*)nullptr, (const float*)nullptr);
    hipLaunchKernelGGL(attn_kernel, dim3(32, 32), dim3(256), 0, stream,
                       QKV, QKV + (size_t)Mv * Dv, QKV + 2 * (size_t)Mv * Dv, am, CTX);
    hipLaunchKernelGGL(gemm_bt_kernel<1>, dim3(32, 16, 1), dim3(256), 0, stream,
                       CTX, Wt + 3 * (size_t)Dv * Dv, (unsigned short*)nullptr, out, bo);
}

// Round 2
// 435.501 us; speedup vs baseline: 1.3804x; 1.3804x over previous
//
#include <hip/hip_runtime.h>
#include <hip/hip_bf16.h>
#include <stdint.h>

// Problem constants (FlaxGPTNeoSelfAttention): B=2, S=2048, D=2048, H=16, HD=128
#define Bv 2
#define Sv 2048
#define Dv 2048
#define Hv 16
#define HDv 128
#define Mv (Bv*Sv)   // 4096 rows for the projection GEMMs

typedef __attribute__((ext_vector_type(8))) short short8;
typedef __attribute__((ext_vector_type(4))) short short4v;
typedef __attribute__((ext_vector_type(4))) float f32x4;

__device__ __forceinline__ unsigned short bf16_rne(float f) {
    union { float f; uint32_t u; } c; c.f = f;
    uint32_t u = c.u;
    u += 0x7fffu + ((u >> 16) & 1u);   // round-to-nearest-even (inputs are finite randoms)
    return (unsigned short)(u >> 16);
}

__device__ __forceinline__ void gload16(const void* g, void* l) {
    // async global->LDS, 16B per lane; LDS dest = wave-uniform base + lane*16
    __builtin_amdgcn_global_load_lds((const __attribute__((address_space(1))) void*)g,
                                     (__attribute__((address_space(3))) void*)l, 16, 0, 0);
}

// ---------------- kernel 1: hidden_states fp32 -> bf16 ----------------
__global__ void cvt_x_kernel(const float* __restrict__ x, unsigned short* __restrict__ xb) {
    int i = (blockIdx.x * 256 + threadIdx.x) * 4;
    float4 v = *(const float4*)(x + i);
    short4v o;
    o[0] = (short)bf16_rne(v.x);
    o[1] = (short)bf16_rne(v.y);
    o[2] = (short)bf16_rne(v.z);
    o[3] = (short)bf16_rne(v.w);
    *(short4v*)(xb + i) = o;
}

// ---------------- kernel 2: weights fp32 -> bf16, transposed Wt[n][k] ----------------
__global__ void cvt_wt_kernel(const float* __restrict__ w0, const float* __restrict__ w1,
                              const float* __restrict__ w2, const float* __restrict__ w3,
                              unsigned short* __restrict__ wt) {
    __shared__ unsigned short t[64][65];
    int z = blockIdx.z;
    const float* w = (z == 0) ? w0 : (z == 1) ? w1 : (z == 2) ? w2 : w3;
    unsigned short* o = wt + (size_t)z * Dv * Dv;
    int k0 = blockIdx.x * 64, n0 = blockIdx.y * 64;
    for (int i = threadIdx.x; i < 4096; i += 256) {
        int r = i >> 6, c = i & 63;
        t[r][c] = bf16_rne(w[(size_t)(k0 + r) * Dv + n0 + c]);
    }
    __syncthreads();
    for (int i = threadIdx.x; i < 4096; i += 256) {
        int r = i >> 6, c = i & 63;
        o[(size_t)(n0 + r) * Dv + k0 + c] = t[c][r];
    }
}

// ---------------- kernel 2b: V (bf16 [4096][2048]) -> VT per batch ([b*2048+c][s]) ----------------
__global__ void vt_kernel(const unsigned short* __restrict__ V, unsigned short* __restrict__ VT) {
    __shared__ unsigned short t[64 * 64];   // XOR chunk-swizzled 64x64 tile
    const int tid = threadIdx.x;
    const int b = blockIdx.z;
    const int s0 = blockIdx.x * 64, c0 = blockIdx.y * 64;
    const unsigned short* Vb = V + (size_t)b * Sv * Dv;
    unsigned short* VTb = VT + (size_t)b * Dv * Sv;
    #pragma unroll
    for (int ii = 0; ii < 2; ++ii) {
        int i = tid + ii * 256;
        int r = i >> 3, ch = i & 7;            // row in tile, 8-short chunk
        short8 v = *(const short8*)&Vb[(size_t)(s0 + r) * Dv + c0 + ch * 8];
        *(short8*)&t[r * 64 + ((ch ^ (r & 7)) << 3)] = v;
    }
    __syncthreads();
    #pragma unroll
    for (int ii = 0; ii < 2; ++ii) {
        int o = tid + ii * 256;
        int orow = o >> 3, och = o & 7;        // output row = c index, chunk along s
        short8 v;
        #pragma unroll
        for (int j = 0; j < 8; ++j) {
            int r = och * 8 + j;               // source tile row (s index)
            int c = orow;                      // source tile col (c index)
            v[j] = (short)t[r * 64 + ((((c >> 3) ^ (r & 7)) << 3) | (c & 7))];
        }
        *(short8*)&VTb[(size_t)(c0 + orow) * Sv + s0 + och * 8] = v;
    }
}

// ---------------- kernel 3/5: GEMM  C[M][N] = A[M][K] @ Wt[N][K]^T ----------------
// 128x128 tile, BK=32, 4 waves (2x2), 16x16x32 bf16 MFMA.
template<int FOUT>
__global__ __launch_bounds__(256) void gemm_bt_kernel(
    const unsigned short* __restrict__ A,
    const unsigned short* __restrict__ WtBase,
    unsigned short* __restrict__ CbBase,
    float* __restrict__ Cf,
    const float* __restrict__ bias)
{
    __shared__ unsigned short lA[128 * 32];
    __shared__ unsigned short lB[128 * 32];
    const int tid = threadIdx.x;
    const int wv = tid >> 6, ln = tid & 63;
    const int lr = ln & 15, lg = ln >> 4;
    const int wm = wv >> 1, wn = wv & 1;
    const int m0 = blockIdx.x * 128, n0 = blockIdx.y * 128;
    const int z = blockIdx.z;
    const unsigned short* Wt = WtBase + (size_t)z * Dv * Dv;
    unsigned short* Cb = CbBase + (size_t)z * (size_t)Mv * Dv;

    const int srow = tid >> 2;
    const int scol = (tid & 3) * 8;

    f32x4 acc[4][4];
    #pragma unroll
    for (int m = 0; m < 4; m++)
        #pragma unroll
        for (int n = 0; n < 4; n++)
            acc[m][n] = (f32x4){0.f, 0.f, 0.f, 0.f};

    for (int kt = 0; kt < Dv; kt += 32) {
        gload16(A  + (size_t)(m0 +      srow) * Dv + kt + scol, &lA[wv * 512]);
        gload16(A  + (size_t)(m0 + 64 + srow) * Dv + kt + scol, &lA[2048 + wv * 512]);
        gload16(Wt + (size_t)(n0 +      srow) * Dv + kt + scol, &lB[wv * 512]);
        gload16(Wt + (size_t)(n0 + 64 + srow) * Dv + kt + scol, &lB[2048 + wv * 512]);
        __syncthreads();

        short8 af[4], bfv[4];
        #pragma unroll
        for (int m = 0; m < 4; m++)
            af[m] = *(const short8*)&lA[(wm * 64 + m * 16 + lr) * 32 + lg * 8];
        #pragma unroll
        for (int n = 0; n < 4; n++)
            bfv[n] = *(const short8*)&lB[(wn * 64 + n * 16 + lr) * 32 + lg * 8];
        #pragma unroll
        for (int m = 0; m < 4; m++)
            #pragma unroll
            for (int n = 0; n < 4; n++)
                acc[m][n] = __builtin_amdgcn_mfma_f32_16x16x32_bf16(af[m], bfv[n], acc[m][n], 0, 0, 0);
        __syncthreads();
    }

    #pragma unroll
    for (int m = 0; m < 4; m++) {
        #pragma unroll
        for (int n = 0; n < 4; n++) {
            int row = m0 + wm * 64 + m * 16 + lg * 4;
            int col = n0 + wn * 64 + n * 16 + lr;
            #pragma unroll
            for (int r = 0; r < 4; r++) {
                if (FOUT)
                    Cf[(size_t)(row + r) * Dv + col] = acc[m][n][r] + bias[col];
                else
                    Cb[(size_t)(row + r) * Dv + col] = bf16_rne(acc[m][n][r]);
            }
        }
    }
}

// ---------------- kernel 4: causal flash attention (swapped QK^T, in-reg softmax) ----------------
// Block = 256 thr (4 waves); one (b,h), 64 q rows (16/wave). KVBLK=32.
// acc holds ctx^T: lane (lr,lg): col q=lr, rows n = nt2*16 + lg*4 + r.
__global__ __launch_bounds__(256) void attn_kernel(
    const unsigned short* __restrict__ Q, const unsigned short* __restrict__ K,
    const unsigned short* __restrict__ VT, const int* __restrict__ pmask,
    unsigned short* __restrict__ CTX)
{
    __shared__ unsigned short lK[32 * 128];    // K tile, chunk-swizzled (ch^(row&7))
    __shared__ unsigned short lVt[128 * 32];   // V^T tile, chunk-swizzled (ch^(row&3))
    __shared__ int lPm[32];

    const int tid = threadIdx.x, wv = tid >> 6, ln = tid & 63;
    const int lr = ln & 15, lg = ln >> 4;
    const int bh = blockIdx.y;
    const int b = bh >> 4, h = bh & 15;
    const int q0 = (gridDim.x - 1 - blockIdx.x) * 64;   // heavy blocks launch first
    const int qw0 = q0 + wv * 16;
    const size_t hoff  = (size_t)b * Sv * Dv + (size_t)h * HDv;
    const size_t vtoff = ((size_t)b * Dv + (size_t)h * HDv) * Sv;

    // Q B-fragments: lane holds Q row (qw0+lr), d = ds*32 + lg*8
    short8 qf[4];
    #pragma unroll
    for (int ds = 0; ds < 4; ds++)
        qf[ds] = *(const short8*)&Q[hoff + (size_t)(qw0 + lr) * Dv + ds * 32 + lg * 8];

    f32x4 acc[8];
    #pragma unroll
    for (int n = 0; n < 8; n++) acc[n] = (f32x4){0.f, 0.f, 0.f, 0.f};
    float mrow = -3.0e38f, lrow = 0.f;          // per-lane, q = qw0 + lr
    const float CS = 0.12751744f;               // (1/sqrt(128)) * log2(e)
    const int qg = qw0 + lr;
    const int nt = (q0 + 64) >> 5;
    const int srcA = lr + ((lg & 1) << 5);      // P-exchange source lanes
    const int srcB = srcA + 16;
    const bool hiSel = (lg >= 2);

    for (int t = 0; t < nt; ++t) {
        const int kv0 = t << 5;
        if (tid < 32) lPm[tid] = pmask[b * Sv + kv0 + tid];
        // stage K [32][128] (16 chunks/row, swizzled source) and VT [128][32] (4 chunks/row)
        #pragma unroll
        for (int ii = 0; ii < 2; ++ii) {
            int slot = ii * 256 + wv * 64 + ln;
            int krow = slot >> 4, kch = slot & 15;
            gload16(K + hoff + (size_t)(kv0 + krow) * Dv + ((kch ^ (krow & 7)) << 3),
                    &lK[(ii * 256 + wv * 64) * 8]);
            int vrow = slot >> 2, vch = slot & 3;
            gload16(VT + vtoff + (size_t)vrow * Sv + kv0 + ((vch ^ (vrow & 3)) << 3),
                    &lVt[(ii * 256 + wv * 64) * 8]);
        }
        __syncthreads();

        // S^T = K @ Q^T : lane holds q = lr, kv rows = t2*16 + lg*4 + r
        f32x4 st[2];
        #pragma unroll
        for (int t2 = 0; t2 < 2; ++t2) {
            f32x4 s = (f32x4){0.f, 0.f, 0.f, 0.f};
            const int krow = t2 * 16 + lr;
            #pragma unroll
            for (int ds = 0; ds < 4; ++ds) {
                int ch = ds * 4 + lg;
                short8 kf = *(const short8*)&lK[krow * 128 + ((ch ^ (krow & 7)) << 3)];
                s = __builtin_amdgcn_mfma_f32_16x16x32_bf16(kf, qf[ds], s, 0, 0, 0);
            }
            st[t2] = s;
        }

        // mask + scale (exp2 domain)
        float tv[2][4];
        #pragma unroll
        for (int t2 = 0; t2 < 2; ++t2)
            #pragma unroll
            for (int r = 0; r < 4; ++r) {
                int kvl = t2 * 16 + lg * 4 + r;
                bool ok = ((kv0 + kvl) <= qg) && (lPm[kvl] != 0);
                tv[t2][r] = ok ? st[t2][r] * CS : -1.0e30f;
            }

        // online softmax (per-lane row q=lr; combine lg groups via shfl)
        float rmax = tv[0][0];
        #pragma unroll
        for (int t2 = 0; t2 < 2; ++t2)
            #pragma unroll
            for (int r = 0; r < 4; ++r) rmax = fmaxf(rmax, tv[t2][r]);
        rmax = fmaxf(rmax, __shfl_xor(rmax, 16, 64));
        rmax = fmaxf(rmax, __shfl_xor(rmax, 32, 64));
        float mn = fmaxf(mrow, rmax);
        float alpha = exp2f(mrow - mn);
        mrow = mn;

        float p[2][4]; float psum = 0.f;
        #pragma unroll
        for (int t2 = 0; t2 < 2; ++t2)
            #pragma unroll
            for (int r = 0; r < 4; ++r) {
                p[t2][r] = exp2f(tv[t2][r] - mn);
                psum += p[t2][r];
            }
        psum += __shfl_xor(psum, 16, 64);
        psum += __shfl_xor(psum, 32, 64);
        lrow = lrow * alpha + psum;
        #pragma unroll
        for (int n = 0; n < 8; n++)
            #pragma unroll
            for (int r = 0; r < 4; r++) acc[n][r] *= alpha;

        // pack P to bf16 pairs: pk[t2][pp] = (p[2pp] lo | p[2pp+1] hi)
        uint32_t pk[2][2];
        #pragma unroll
        for (int t2 = 0; t2 < 2; ++t2)
            #pragma unroll
            for (int pp = 0; pp < 2; ++pp)
                pk[t2][pp] = (uint32_t)bf16_rne(p[t2][2 * pp]) |
                             ((uint32_t)bf16_rne(p[t2][2 * pp + 1]) << 16);

        // exchange to B-fragment of P^T: a[d] = pk[lg>>1][d&1] from lane lr + 16*((lg&1)*2 + (d>>1))
        uint32_t a0lo = (uint32_t)__shfl((int)pk[0][0], srcA, 64);
        uint32_t a0hi = (uint32_t)__shfl((int)pk[1][0], srcA, 64);
        uint32_t a1lo = (uint32_t)__shfl((int)pk[0][1], srcA, 64);
        uint32_t a1hi = (uint32_t)__shfl((int)pk[1][1], srcA, 64);
        uint32_t a2lo = (uint32_t)__shfl((int)pk[0][0], srcB, 64);
        uint32_t a2hi = (uint32_t)__shfl((int)pk[1][0], srcB, 64);
        uint32_t a3lo = (uint32_t)__shfl((int)pk[0][1], srcB, 64);
        uint32_t a3hi = (uint32_t)__shfl((int)pk[1][1], srcB, 64);
        union { uint32_t u[4]; short8 s; } pa;
        pa.u[0] = hiSel ? a0hi : a0lo;
        pa.u[1] = hiSel ? a1hi : a1lo;
        pa.u[2] = hiSel ? a2hi : a2lo;
        pa.u[3] = hiSel ? a3hi : a3lo;

        // PV: ctx^T += V^T @ P^T  (A = VT rows n, B = P^T cols q)
        #pragma unroll
        for (int n = 0; n < 8; n++) {
            int vrow = n * 16 + lr;
            short8 av = *(const short8*)&lVt[vrow * 32 + ((lg ^ (vrow & 3)) << 3)];
            acc[n] = __builtin_amdgcn_mfma_f32_16x16x32_bf16(av, pa.s, acc[n], 0, 0, 0);
        }
        __syncthreads();
    }

    // epilogue: ctx[q][n] = acc^T / lrow ; 8B stores (4 consecutive n per lane)
    float inv = 1.0f / lrow;
    #pragma unroll
    for (int n = 0; n < 8; n++) {
        short4v o;
        #pragma unroll
        for (int r = 0; r < 4; r++) o[r] = (short)bf16_rne(acc[n][r] * inv);
        *(short4v*)&CTX[hoff + (size_t)qg * Dv + n * 16 + lg * 4] = o;
    }
}

// ---------------- launcher ----------------
extern "C" void kernel_launch(void* const* d_in, const int* in_sizes, int n_in,
                              void* d_out, int out_size, void* d_ws, size_t ws_size,
                              hipStream_t stream) {
    const float* hs  = (const float*)d_in[0];
    const int*   am  = (const int*)d_in[1];
    const float* wq  = (const float*)d_in[2];
    const float* wk  = (const float*)d_in[3];
    const float* wv_ = (const float*)d_in[4];
    const float* wo  = (const float*)d_in[5];
    const float* bo  = (const float*)d_in[6];
    float* out = (float*)d_out;

    char* ws = (char*)d_ws;
    unsigned short* Xb  = (unsigned short*)ws;                               // 16 MiB: X bf16; later reused as VT
    unsigned short* Wt  = (unsigned short*)(ws + (size_t)16 * 1024 * 1024);  // 32 MiB: 4x Wt bf16
    unsigned short* QKV = (unsigned short*)(ws + (size_t)48 * 1024 * 1024);  // 48 MiB: Q,K,V bf16
    unsigned short* CTX = (unsigned short*)(ws + (size_t)96 * 1024 * 1024);  // 16 MiB: ctx bf16
    unsigned short* VT  = Xb;                                                // alias (Xb dead after QKV GEMM)

    hipLaunchKernelGGL(cvt_x_kernel, dim3(Mv * Dv / 4 / 256), dim3(256), 0, stream, hs, Xb);
    hipLaunchKernelGGL(cvt_wt_kernel, dim3(32, 32, 4), dim3(256), 0, stream, wq, wk, wv_, wo, Wt);
    hipLaunchKernelGGL(gemm_bt_kernel<0>, dim3(32, 16, 3), dim3(256), 0, stream,
                       Xb, Wt, QKV, (float*)nullptr, (const float*)nullptr);
    hipLaunchKernelGGL(vt_kernel, dim3(32, 32, 2), dim3(256), 0, stream,
                       QKV + 2 * (size_t)Mv * Dv, VT);
    hipLaunchKernelGGL(attn_kernel, dim3(32, 32), dim3(256), 0, stream,
                       QKV, QKV + (size_t)Mv * Dv, VT, am, CTX);
    hipLaunchKernelGGL(gemm_bt_kernel<1>, dim3(32, 16, 1), dim3(256), 0, stream,
                       CTX, Wt + 3 * (size_t)Dv * Dv, (unsigned short*)nullptr, out, bo);
}

// Round 3
// 292.088 us; speedup vs baseline: 2.0582x; 1.4910x over previous
//
#include <hip/hip_runtime.h>
#include <hip/hip_bf16.h>
#include <stdint.h>

// Problem constants (FlaxGPTNeoSelfAttention): B=2, S=2048, D=2048, H=16, HD=128
#define Bv 2
#define Sv 2048
#define Dv 2048
#define Hv 16
#define HDv 128
#define Mv (Bv*Sv)   // 4096 rows for the projection GEMMs

typedef __attribute__((ext_vector_type(8))) short short8;
typedef __attribute__((ext_vector_type(4))) short short4v;
typedef __attribute__((ext_vector_type(4))) float f32x4;

__device__ __forceinline__ unsigned short bf16_rne(float f) {
    union { float f; uint32_t u; } c; c.f = f;
    uint32_t u = c.u;
    u += 0x7fffu + ((u >> 16) & 1u);   // round-to-nearest-even (inputs are finite randoms)
    return (unsigned short)(u >> 16);
}

__device__ __forceinline__ void gload16(const void* g, void* l) {
    // async global->LDS, 16B per lane; LDS dest = wave-uniform base + lane*16
    __builtin_amdgcn_global_load_lds((const __attribute__((address_space(1))) void*)g,
                                     (__attribute__((address_space(3))) void*)l, 16, 0, 0);
}

// ---------------- kernel 1: hidden_states fp32 -> bf16 ----------------
__global__ void cvt_x_kernel(const float* __restrict__ x, unsigned short* __restrict__ xb) {
    int i = (blockIdx.x * 256 + threadIdx.x) * 4;
    float4 v = *(const float4*)(x + i);
    short4v o;
    o[0] = (short)bf16_rne(v.x);
    o[1] = (short)bf16_rne(v.y);
    o[2] = (short)bf16_rne(v.z);
    o[3] = (short)bf16_rne(v.w);
    *(short4v*)(xb + i) = o;
}

// ---------------- kernel 2: weights fp32 -> bf16, transposed Wt[n][k] ----------------
__global__ void cvt_wt_kernel(const float* __restrict__ w0, const float* __restrict__ w1,
                              const float* __restrict__ w2, const float* __restrict__ w3,
                              unsigned short* __restrict__ wt) {
    __shared__ unsigned short t[64][65];
    int z = blockIdx.z;
    const float* w = (z == 0) ? w0 : (z == 1) ? w1 : (z == 2) ? w2 : w3;
    unsigned short* o = wt + (size_t)z * Dv * Dv;
    int k0 = blockIdx.x * 64, n0 = blockIdx.y * 64;
    for (int i = threadIdx.x; i < 4096; i += 256) {
        int r = i >> 6, c = i & 63;
        t[r][c] = bf16_rne(w[(size_t)(k0 + r) * Dv + n0 + c]);
    }
    __syncthreads();
    for (int i = threadIdx.x; i < 4096; i += 256) {
        int r = i >> 6, c = i & 63;
        o[(size_t)(n0 + r) * Dv + k0 + c] = t[c][r];
    }
}

// ---------------- kernel 2b: V (bf16 [4096][2048]) -> VT per batch ([b*2048+c][s]) ----------------
__global__ void vt_kernel(const unsigned short* __restrict__ V, unsigned short* __restrict__ VT) {
    __shared__ unsigned short t[64 * 64];   // XOR chunk-swizzled 64x64 tile
    const int tid = threadIdx.x;
    const int b = blockIdx.z;
    const int s0 = blockIdx.x * 64, c0 = blockIdx.y * 64;
    const unsigned short* Vb = V + (size_t)b * Sv * Dv;
    unsigned short* VTb = VT + (size_t)b * Dv * Sv;
    #pragma unroll
    for (int ii = 0; ii < 2; ++ii) {
        int i = tid + ii * 256;
        int r = i >> 3, ch = i & 7;            // row in tile, 8-short chunk
        short8 v = *(const short8*)&Vb[(size_t)(s0 + r) * Dv + c0 + ch * 8];
        *(short8*)&t[r * 64 + ((ch ^ (r & 7)) << 3)] = v;
    }
    __syncthreads();
    #pragma unroll
    for (int ii = 0; ii < 2; ++ii) {
        int o = tid + ii * 256;
        int orow = o >> 3, och = o & 7;        // output row = c index, chunk along s
        short8 v;
        #pragma unroll
        for (int j = 0; j < 8; ++j) {
            int r = och * 8 + j;               // source tile row (s index)
            int c = orow;                      // source tile col (c index)
            v[j] = (short)t[r * 64 + ((((c >> 3) ^ (r & 7)) << 3) | (c & 7))];
        }
        *(short8*)&VTb[(size_t)(c0 + orow) * Sv + s0 + och * 8] = v;
    }
}

// ---------------- kernel 3/5: GEMM  C[M][N] = A[M][K] @ Wt[N][K]^T ----------------
// 128x128 tile, BK=32, 4 waves (2x2), 16x16x32 bf16 MFMA.
template<int FOUT>
__global__ __launch_bounds__(256) void gemm_bt_kernel(
    const unsigned short* __restrict__ A,
    const unsigned short* __restrict__ WtBase,
    unsigned short* __restrict__ CbBase,
    float* __restrict__ Cf,
    const float* __restrict__ bias)
{
    __shared__ unsigned short lA[128 * 32];
    __shared__ unsigned short lB[128 * 32];
    const int tid = threadIdx.x;
    const int wv = tid >> 6, ln = tid & 63;
    const int lr = ln & 15, lg = ln >> 4;
    const int wm = wv >> 1, wn = wv & 1;
    const int m0 = blockIdx.x * 128, n0 = blockIdx.y * 128;
    const int z = blockIdx.z;
    const unsigned short* Wt = WtBase + (size_t)z * Dv * Dv;
    unsigned short* Cb = CbBase + (size_t)z * (size_t)Mv * Dv;

    const int srow = tid >> 2;
    const int scol = (tid & 3) * 8;

    f32x4 acc[4][4];
    #pragma unroll
    for (int m = 0; m < 4; m++)
        #pragma unroll
        for (int n = 0; n < 4; n++)
            acc[m][n] = (f32x4){0.f, 0.f, 0.f, 0.f};

    for (int kt = 0; kt < Dv; kt += 32) {
        gload16(A  + (size_t)(m0 +      srow) * Dv + kt + scol, &lA[wv * 512]);
        gload16(A  + (size_t)(m0 + 64 + srow) * Dv + kt + scol, &lA[2048 + wv * 512]);
        gload16(Wt + (size_t)(n0 +      srow) * Dv + kt + scol, &lB[wv * 512]);
        gload16(Wt + (size_t)(n0 + 64 + srow) * Dv + kt + scol, &lB[2048 + wv * 512]);
        __syncthreads();

        short8 af[4], bfv[4];
        #pragma unroll
        for (int m = 0; m < 4; m++)
            af[m] = *(const short8*)&lA[(wm * 64 + m * 16 + lr) * 32 + lg * 8];
        #pragma unroll
        for (int n = 0; n < 4; n++)
            bfv[n] = *(const short8*)&lB[(wn * 64 + n * 16 + lr) * 32 + lg * 8];
        #pragma unroll
        for (int m = 0; m < 4; m++)
            #pragma unroll
            for (int n = 0; n < 4; n++)
                acc[m][n] = __builtin_amdgcn_mfma_f32_16x16x32_bf16(af[m], bfv[n], acc[m][n], 0, 0, 0);
        __syncthreads();
    }

    #pragma unroll
    for (int m = 0; m < 4; m++) {
        #pragma unroll
        for (int n = 0; n < 4; n++) {
            int row = m0 + wm * 64 + m * 16 + lg * 4;
            int col = n0 + wn * 64 + n * 16 + lr;
            #pragma unroll
            for (int r = 0; r < 4; r++) {
                if (FOUT)
                    Cf[(size_t)(row + r) * Dv + col] = acc[m][n][r] + bias[col];
                else
                    Cb[(size_t)(row + r) * Dv + col] = bf16_rne(acc[m][n][r]);
            }
        }
    }
}

// ---------------- kernel 4: causal flash attention ----------------
// 2-phase pipelined, double-buffered LDS, KVBLK=64, swapped QK^T, in-reg softmax.
// Block = 256 thr (4 waves); one (b,h), 64 q rows (16/wave).
// acc holds ctx^T: lane (lr,lg): col q=lr, HD rows n*16 + lg*4 + r.
__global__ __launch_bounds__(256) void attn_kernel(
    const unsigned short* __restrict__ Q, const unsigned short* __restrict__ K,
    const unsigned short* __restrict__ VT, const int* __restrict__ pmask,
    unsigned short* __restrict__ CTX)
{
    __shared__ unsigned short lK[2][64 * 128];    // K tiles, chunk-swizzled (ch^(row&7))
    __shared__ unsigned short lVt[2][128 * 64];   // V^T tiles, chunk-swizzled (ch^(row&7))
    __shared__ int lPmB[2][64];

    const int tid = threadIdx.x, wv = tid >> 6, ln = tid & 63;
    const int lr = ln & 15, lg = ln >> 4;
    // XCD-aware remap: XCD x hosts bh in {4x..4x+3}; heavy q-tiles (large q0) first.
    const int L = blockIdx.x;
    const int bh = (L & 7) * 4 + ((L >> 3) & 3);
    const int b = bh >> 4, h = bh & 15;
    const int q0 = (31 - (L >> 5)) * 64;
    const int qw0 = q0 + wv * 16;
    const size_t hoff  = (size_t)b * Sv * Dv + (size_t)h * HDv;
    const size_t vtoff = ((size_t)b * Dv + (size_t)h * HDv) * Sv;

    // Q B-fragments: lane holds Q row (qw0+lr), d = ds*32 + lg*8
    short8 qf[4];
    #pragma unroll
    for (int ds = 0; ds < 4; ds++)
        qf[ds] = *(const short8*)&Q[hoff + (size_t)(qw0 + lr) * Dv + ds * 32 + lg * 8];

    // per-lane staging source offsets (pre-swizzled global addresses, linear LDS dest)
    size_t koff[4], voff[4];
    #pragma unroll
    for (int ii = 0; ii < 4; ++ii) {
        int slot = ii * 256 + wv * 64 + ln;
        int krow = slot >> 4, kch = slot & 15;            // K: 64 rows x 16 chunks
        koff[ii] = hoff + (size_t)krow * Dv + ((kch ^ (krow & 7)) << 3);
        int vrow = slot >> 3, vch = slot & 7;             // VT: 128 rows x 8 chunks
        voff[ii] = vtoff + (size_t)vrow * Sv + ((vch ^ (vrow & 7)) << 3);
    }

    auto STAGE = [&](int t, int buf) {
        const size_t kadd = (size_t)(t << 6) * Dv;
        const int vadd = t << 6;
        unsigned short* kb = &lK[buf][0];
        unsigned short* vb = &lVt[buf][0];
        #pragma unroll
        for (int ii = 0; ii < 4; ++ii) {
            gload16(K + koff[ii] + kadd, kb + (ii * 256 + wv * 64) * 8);
            gload16(VT + voff[ii] + vadd, vb + (ii * 256 + wv * 64) * 8);
        }
        if (tid < 64) lPmB[buf][tid] = pmask[b * Sv + (t << 6) + tid];
    };

    f32x4 acc[8];
    #pragma unroll
    for (int n = 0; n < 8; n++) acc[n] = (f32x4){0.f, 0.f, 0.f, 0.f};
    float mrow = -3.0e38f, lrow = 0.f;          // per-lane, q = qw0 + lr
    const float CS = 0.12751744f;               // (1/sqrt(128)) * log2(e)
    const int qg = qw0 + lr;
    const int nt = (q0 >> 6) + 1;
    const int srcA = lr + ((lg & 1) << 5);      // P-exchange source lanes
    const int srcB = srcA + 16;
    const bool hiSel = (lg >= 2);

    STAGE(0, 0);
    __syncthreads();
    int cur = 0;

    for (int t = 0; t < nt; ++t) {
        if (t + 1 < nt) STAGE(t + 1, cur ^ 1);   // issue-early: latency hides under compute

        const int kv0 = t << 6;
        const unsigned short* kb = &lK[cur][0];
        const unsigned short* vb = &lVt[cur][0];
        const int* pm = &lPmB[cur][0];

        // S^T = K @ Q^T : lane holds q = lr, kv rows = t2*16 + lg*4 + r
        f32x4 st[4];
        #pragma unroll
        for (int t2 = 0; t2 < 4; ++t2) st[t2] = (f32x4){0.f, 0.f, 0.f, 0.f};
        __builtin_amdgcn_s_setprio(1);
        #pragma unroll
        for (int t2 = 0; t2 < 4; ++t2) {
            const int krow = t2 * 16 + lr;
            #pragma unroll
            for (int ds = 0; ds < 4; ++ds) {
                const int ch = ds * 4 + lg;
                short8 kf = *(const short8*)&kb[krow * 128 + ((ch ^ (krow & 7)) << 3)];
                st[t2] = __builtin_amdgcn_mfma_f32_16x16x32_bf16(kf, qf[ds], st[t2], 0, 0, 0);
            }
        }
        __builtin_amdgcn_s_setprio(0);

        // mask + scale (exp2 domain)
        float tv[4][4];
        #pragma unroll
        for (int t2 = 0; t2 < 4; ++t2)
            #pragma unroll
            for (int r = 0; r < 4; ++r) {
                int kvl = t2 * 16 + lg * 4 + r;
                bool ok = ((kv0 + kvl) <= qg) && (pm[kvl] != 0);
                tv[t2][r] = ok ? st[t2][r] * CS : -1.0e30f;
            }

        // online softmax (per-lane row q=lr; lanes {lr,lr+16,lr+32,lr+48} share a row)
        float rmax = tv[0][0];
        #pragma unroll
        for (int t2 = 0; t2 < 4; ++t2)
            #pragma unroll
            for (int r = 0; r < 4; ++r) rmax = fmaxf(rmax, tv[t2][r]);
        rmax = fmaxf(rmax, __shfl_xor(rmax, 16, 64));
        rmax = fmaxf(rmax, __shfl_xor(rmax, 32, 64));

        // T13 defer-max: skip rescale when tile max grew < 8 (exp2 headroom 256, fine in bf16)
        if (!__all(rmax - mrow <= 8.0f)) {
            float mn = fmaxf(mrow, rmax);
            float alpha = exp2f(mrow - mn);
            mrow = mn;
            lrow *= alpha;
            #pragma unroll
            for (int n = 0; n < 8; n++)
                #pragma unroll
                for (int r = 0; r < 4; r++) acc[n][r] *= alpha;
        }

        float p[4][4]; float psum = 0.f;
        #pragma unroll
        for (int t2 = 0; t2 < 4; ++t2)
            #pragma unroll
            for (int r = 0; r < 4; ++r) {
                p[t2][r] = exp2f(tv[t2][r] - mrow);
                psum += p[t2][r];
            }
        psum += __shfl_xor(psum, 16, 64);
        psum += __shfl_xor(psum, 32, 64);
        lrow += psum;

        // pack P to bf16 pairs: pk[t2][pp] = (p[2pp] lo | p[2pp+1] hi)
        uint32_t pk[4][2];
        #pragma unroll
        for (int t2 = 0; t2 < 4; ++t2)
            #pragma unroll
            for (int pp = 0; pp < 2; ++pp)
                pk[t2][pp] = (uint32_t)bf16_rne(p[t2][2 * pp]) |
                             ((uint32_t)bf16_rne(p[t2][2 * pp + 1]) << 16);

        // exchange to B-fragments of P^T (kv slices ks=0: kv 0..31 from pk[0..1], ks=1: kv 32..63 from pk[2..3])
        union U { uint32_t u[4]; short8 s; } pa0, pa1;
        {
            uint32_t l0 = (uint32_t)__shfl((int)pk[0][0], srcA, 64), h0 = (uint32_t)__shfl((int)pk[1][0], srcA, 64);
            uint32_t l1 = (uint32_t)__shfl((int)pk[0][1], srcA, 64), h1 = (uint32_t)__shfl((int)pk[1][1], srcA, 64);
            uint32_t l2 = (uint32_t)__shfl((int)pk[0][0], srcB, 64), h2 = (uint32_t)__shfl((int)pk[1][0], srcB, 64);
            uint32_t l3 = (uint32_t)__shfl((int)pk[0][1], srcB, 64), h3 = (uint32_t)__shfl((int)pk[1][1], srcB, 64);
            pa0.u[0] = hiSel ? h0 : l0; pa0.u[1] = hiSel ? h1 : l1;
            pa0.u[2] = hiSel ? h2 : l2; pa0.u[3] = hiSel ? h3 : l3;
        }
        {
            uint32_t l0 = (uint32_t)__shfl((int)pk[2][0], srcA, 64), h0 = (uint32_t)__shfl((int)pk[3][0], srcA, 64);
            uint32_t l1 = (uint32_t)__shfl((int)pk[2][1], srcA, 64), h1 = (uint32_t)__shfl((int)pk[3][1], srcA, 64);
            uint32_t l2 = (uint32_t)__shfl((int)pk[2][0], srcB, 64), h2 = (uint32_t)__shfl((int)pk[3][0], srcB, 64);
            uint32_t l3 = (uint32_t)__shfl((int)pk[2][1], srcB, 64), h3 = (uint32_t)__shfl((int)pk[3][1], srcB, 64);
            pa1.u[0] = hiSel ? h0 : l0; pa1.u[1] = hiSel ? h1 : l1;
            pa1.u[2] = hiSel ? h2 : l2; pa1.u[3] = hiSel ? h3 : l3;
        }

        // PV: ctx^T += V^T @ P^T  (A = VT rows, B = P^T cols q); K=64 -> 2 MFMA per n-block
        __builtin_amdgcn_s_setprio(1);
        #pragma unroll
        for (int n = 0; n < 8; n++) {
            const int vrow = n * 16 + lr;
            short8 a0 = *(const short8*)&vb[vrow * 64 + ((lg ^ (vrow & 7)) << 3)];
            acc[n] = __builtin_amdgcn_mfma_f32_16x16x32_bf16(a0, pa0.s, acc[n], 0, 0, 0);
            short8 a1 = *(const short8*)&vb[vrow * 64 + (((4 + lg) ^ (vrow & 7)) << 3)];
            acc[n] = __builtin_amdgcn_mfma_f32_16x16x32_bf16(a1, pa1.s, acc[n], 0, 0, 0);
        }
        __builtin_amdgcn_s_setprio(0);

        __syncthreads();   // drains vmcnt for t+1 stage (overlapped with this tile's compute)
        cur ^= 1;
    }

    // epilogue: ctx[q][hd] = acc^T / lrow ; 8B stores (4 consecutive hd per lane)
    float inv = 1.0f / lrow;
    #pragma unroll
    for (int n = 0; n < 8; n++) {
        short4v o;
        #pragma unroll
        for (int r = 0; r < 4; r++) o[r] = (short)bf16_rne(acc[n][r] * inv);
        *(short4v*)&CTX[hoff + (size_t)qg * Dv + n * 16 + lg * 4] = o;
    }
}

// ---------------- launcher ----------------
extern "C" void kernel_launch(void* const* d_in, const int* in_sizes, int n_in,
                              void* d_out, int out_size, void* d_ws, size_t ws_size,
                              hipStream_t stream) {
    const float* hs  = (const float*)d_in[0];
    const int*   am  = (const int*)d_in[1];
    const float* wq  = (const float*)d_in[2];
    const float* wk  = (const float*)d_in[3];
    const float* wv_ = (const float*)d_in[4];
    const float* wo  = (const float*)d_in[5];
    const float* bo  = (const float*)d_in[6];
    float* out = (float*)d_out;

    char* ws = (char*)d_ws;
    unsigned short* Xb  = (unsigned short*)ws;                               // 16 MiB: X bf16; later reused as VT
    unsigned short* Wt  = (unsigned short*)(ws + (size_t)16 * 1024 * 1024);  // 32 MiB: 4x Wt bf16
    unsigned short* QKV = (unsigned short*)(ws + (size_t)48 * 1024 * 1024);  // 48 MiB: Q,K,V bf16
    unsigned short* CTX = (unsigned short*)(ws + (size_t)96 * 1024 * 1024);  // 16 MiB: ctx bf16
    unsigned short* VT  = Xb;                                                // alias (Xb dead after QKV GEMM)

    hipLaunchKernelGGL(cvt_x_kernel, dim3(Mv * Dv / 4 / 256), dim3(256), 0, stream, hs, Xb);
    hipLaunchKernelGGL(cvt_wt_kernel, dim3(32, 32, 4), dim3(256), 0, stream, wq, wk, wv_, wo, Wt);
    hipLaunchKernelGGL(gemm_bt_kernel<0>, dim3(32, 16, 3), dim3(256), 0, stream,
                       Xb, Wt, QKV, (float*)nullptr, (const float*)nullptr);
    hipLaunchKernelGGL(vt_kernel, dim3(32, 32, 2), dim3(256), 0, stream,
                       QKV + 2 * (size_t)Mv * Dv, VT);
    hipLaunchKernelGGL(attn_kernel, dim3(1024), dim3(256), 0, stream,
                       QKV, QKV + (size_t)Mv * Dv, VT, am, CTX);
    hipLaunchKernelGGL(gemm_bt_kernel<1>, dim3(32, 16, 1), dim3(256), 0, stream,
                       CTX, Wt + 3 * (size_t)Dv * Dv, (unsigned short*)nullptr, out, bo);
}

// Round 4
// 260.172 us; speedup vs baseline: 2.3107x; 1.1227x over previous
//
#include <hip/hip_runtime.h>
#include <hip/hip_bf16.h>
#include <stdint.h>

// Problem constants (FlaxGPTNeoSelfAttention): B=2, S=2048, D=2048, H=16, HD=128
#define Bv 2
#define Sv 2048
#define Dv 2048
#define Hv 16
#define HDv 128
#define Mv (Bv*Sv)   // 4096 rows for the projection GEMMs

typedef __attribute__((ext_vector_type(8))) short short8;
typedef __attribute__((ext_vector_type(4))) short short4v;
typedef __attribute__((ext_vector_type(4))) float f32x4;

__device__ __forceinline__ unsigned short bf16_rne(float f) {
    union { float f; uint32_t u; } c; c.f = f;
    uint32_t u = c.u;
    u += 0x7fffu + ((u >> 16) & 1u);   // round-to-nearest-even
    return (unsigned short)(u >> 16);
}

__device__ __forceinline__ uint32_t cvt_pk_bf16(float lo, float hi) {
    uint32_t r;
    asm("v_cvt_pk_bf16_f32 %0, %1, %2" : "=v"(r) : "v"(lo), "v"(hi));
    return r;
}

__device__ __forceinline__ void gload16(const void* g, void* l) {
    // async global->LDS, 16B per lane; LDS dest = wave-uniform base + lane*16
    __builtin_amdgcn_global_load_lds((const __attribute__((address_space(1))) void*)g,
                                     (__attribute__((address_space(3))) void*)l, 16, 0, 0);
}

// ---------------- kernel 1: hidden_states fp32 -> bf16 ----------------
__global__ void cvt_x_kernel(const float* __restrict__ x, unsigned short* __restrict__ xb) {
    int i = (blockIdx.x * 256 + threadIdx.x) * 4;
    float4 v = *(const float4*)(x + i);
    short4v o;
    o[0] = (short)bf16_rne(v.x);
    o[1] = (short)bf16_rne(v.y);
    o[2] = (short)bf16_rne(v.z);
    o[3] = (short)bf16_rne(v.w);
    *(short4v*)(xb + i) = o;
}

// ---------------- kernel 2: weights fp32 -> bf16, transposed Wt[n][k] ----------------
__global__ void cvt_wt_kernel(const float* __restrict__ w0, const float* __restrict__ w1,
                              const float* __restrict__ w2, const float* __restrict__ w3,
                              unsigned short* __restrict__ wt) {
    __shared__ unsigned short t[64][65];
    int z = blockIdx.z;
    const float* w = (z == 0) ? w0 : (z == 1) ? w1 : (z == 2) ? w2 : w3;
    unsigned short* o = wt + (size_t)z * Dv * Dv;
    int k0 = blockIdx.x * 64, n0 = blockIdx.y * 64;
    for (int i = threadIdx.x; i < 4096; i += 256) {
        int r = i >> 6, c = i & 63;
        t[r][c] = bf16_rne(w[(size_t)(k0 + r) * Dv + n0 + c]);
    }
    __syncthreads();
    for (int i = threadIdx.x; i < 4096; i += 256) {
        int r = i >> 6, c = i & 63;
        o[(size_t)(n0 + r) * Dv + k0 + c] = t[c][r];
    }
}

// ---------------- kernel 3/5: GEMM  C[M][N] = A[M][K] @ Wt[N][K]^T ----------------
// 128x128 tile, BK=32, 4 waves (2x2), 16x16x32 bf16 MFMA.
// FOUT=0: z=0,1 -> bf16 row-major to CbBase; z=2 -> bf16 TRANSPOSED V to VTout ([b][c][s]).
// FOUT=1: fp32 store to Cf with +bias.
template<int FOUT>
__global__ __launch_bounds__(256) void gemm_bt_kernel(
    const unsigned short* __restrict__ A,
    const unsigned short* __restrict__ WtBase,
    unsigned short* __restrict__ CbBase,
    unsigned short* __restrict__ VTout,
    float* __restrict__ Cf,
    const float* __restrict__ bias)
{
    __shared__ unsigned short lA[128 * 32];
    __shared__ unsigned short lB[128 * 32];
    const int tid = threadIdx.x;
    const int wv = tid >> 6, ln = tid & 63;
    const int lr = ln & 15, lg = ln >> 4;
    const int wm = wv >> 1, wn = wv & 1;
    const int m0 = blockIdx.x * 128, n0 = blockIdx.y * 128;
    const int z = blockIdx.z;
    const unsigned short* Wt = WtBase + (size_t)z * Dv * Dv;
    unsigned short* Cb = CbBase + (size_t)z * (size_t)Mv * Dv;

    const int srow = tid >> 2;
    const int scol = (tid & 3) * 8;

    f32x4 acc[4][4];
    #pragma unroll
    for (int m = 0; m < 4; m++)
        #pragma unroll
        for (int n = 0; n < 4; n++)
            acc[m][n] = (f32x4){0.f, 0.f, 0.f, 0.f};

    for (int kt = 0; kt < Dv; kt += 32) {
        gload16(A  + (size_t)(m0 +      srow) * Dv + kt + scol, &lA[wv * 512]);
        gload16(A  + (size_t)(m0 + 64 + srow) * Dv + kt + scol, &lA[2048 + wv * 512]);
        gload16(Wt + (size_t)(n0 +      srow) * Dv + kt + scol, &lB[wv * 512]);
        gload16(Wt + (size_t)(n0 + 64 + srow) * Dv + kt + scol, &lB[2048 + wv * 512]);
        __syncthreads();

        short8 af[4], bfv[4];
        #pragma unroll
        for (int m = 0; m < 4; m++)
            af[m] = *(const short8*)&lA[(wm * 64 + m * 16 + lr) * 32 + lg * 8];
        #pragma unroll
        for (int n = 0; n < 4; n++)
            bfv[n] = *(const short8*)&lB[(wn * 64 + n * 16 + lr) * 32 + lg * 8];
        #pragma unroll
        for (int m = 0; m < 4; m++)
            #pragma unroll
            for (int n = 0; n < 4; n++)
                acc[m][n] = __builtin_amdgcn_mfma_f32_16x16x32_bf16(af[m], bfv[n], acc[m][n], 0, 0, 0);
        __syncthreads();
    }

    #pragma unroll
    for (int m = 0; m < 4; m++) {
        #pragma unroll
        for (int n = 0; n < 4; n++) {
            int row = m0 + wm * 64 + m * 16 + lg * 4;
            int col = n0 + wn * 64 + n * 16 + lr;
            if (FOUT) {
                #pragma unroll
                for (int r = 0; r < 4; r++)
                    Cf[(size_t)(row + r) * Dv + col] = acc[m][n][r] + bias[col];
            } else if (z == 2) {
                // V transposed: VT[b][col][s], 4 consecutive s per lane -> 8B store
                int bb = row >> 11, s = row & (Sv - 1);
                short4v o;
                #pragma unroll
                for (int r = 0; r < 4; r++) o[r] = (short)bf16_rne(acc[m][n][r]);
                *(short4v*)&VTout[((size_t)bb * Dv + col) * Sv + s] = o;
            } else {
                #pragma unroll
                for (int r = 0; r < 4; r++)
                    Cb[(size_t)(row + r) * Dv + col] = bf16_rne(acc[m][n][r]);
            }
        }
    }
}

// ---------------- kernel 4: causal flash attention ----------------
// 8 waves (512 thr), 128 q rows/block (16/wave), KVBLK=64, double-buffered LDS,
// swapped QK^T, in-reg softmax, causal work only on diagonal tiles.
// acc holds ctx^T: lane (lr,lg): q col = lr, HD rows n*16 + lg*4 + r.
__global__ __launch_bounds__(512) void attn_kernel(
    const unsigned short* __restrict__ Q, const unsigned short* __restrict__ K,
    const unsigned short* __restrict__ VT, const int* __restrict__ pmask,
    unsigned short* __restrict__ CTX)
{
    __shared__ unsigned short lK[2][64 * 128];    // K tiles, chunk-swizzled (ch^(row&7))
    __shared__ unsigned short lVt[2][128 * 64];   // V^T tiles, chunk-swizzled (ch^(row&7))
    __shared__ int lPmB[2][64];
    __shared__ int lPmOk[2];

    const int tid = threadIdx.x, wv = tid >> 6, ln = tid & 63;
    const int lr = ln & 15, lg = ln >> 4;
    // 512 blocks: XCD x hosts bh in {4x..4x+3}; per-CU pair (v, v+8) sums to constant work.
    const int L = blockIdx.x;
    const int bh = (L & 7) * 4 + ((L >> 3) & 3);
    const int b = bh >> 4, h = bh & 15;
    const int v = L >> 5;                          // 0..15
    const int qidx = (v < 8) ? (15 - v) : (v - 8);
    const int q0 = qidx * 128;
    const int qw0 = q0 + wv * 16;
    const size_t hoff  = (size_t)b * Sv * Dv + (size_t)h * HDv;
    const size_t vtoff = ((size_t)b * Dv + (size_t)h * HDv) * Sv;

    // Q B-fragments: lane holds Q row (qw0+lr), d = ds*32 + lg*8
    short8 qf[4];
    #pragma unroll
    for (int ds = 0; ds < 4; ds++)
        qf[ds] = *(const short8*)&Q[hoff + (size_t)(qw0 + lr) * Dv + ds * 32 + lg * 8];

    // per-lane staging source offsets (pre-swizzled global addresses, linear LDS dest)
    size_t koff[2], voff[2];
    #pragma unroll
    for (int ii = 0; ii < 2; ++ii) {
        int slot = ii * 512 + wv * 64 + ln;
        int krow = slot >> 4, kch = slot & 15;            // K: 64 rows x 16 chunks
        koff[ii] = hoff + (size_t)krow * Dv + ((kch ^ (krow & 7)) << 3);
        int vrow = slot >> 3, vch = slot & 7;             // VT: 128 rows x 8 chunks
        voff[ii] = vtoff + (size_t)vrow * Sv + ((vch ^ (vrow & 7)) << 3);
    }

    auto STAGE = [&](int t, int buf) {
        const size_t kadd = (size_t)(t << 6) * Dv;
        const int vadd = t << 6;
        unsigned short* kb = &lK[buf][0];
        unsigned short* vb = &lVt[buf][0];
        #pragma unroll
        for (int ii = 0; ii < 2; ++ii) {
            gload16(K + koff[ii] + kadd, kb + (ii * 512 + wv * 64) * 8);
            gload16(VT + voff[ii] + vadd, vb + (ii * 512 + wv * 64) * 8);
        }
        if (wv == 0) {
            int pmv = pmask[b * Sv + (t << 6) + ln];
            lPmB[buf][ln] = pmv;
            unsigned long long bal = __ballot(pmv != 0);
            if (ln == 0) lPmOk[buf] = (bal == ~0ull) ? 1 : 0;
        }
    };

    f32x4 acc[8];
    #pragma unroll
    for (int n = 0; n < 8; n++) acc[n] = (f32x4){0.f, 0.f, 0.f, 0.f};
    float mrow = -3.0e38f, lrow = 0.f;          // per-lane, q = qw0 + lr
    const float CS = 0.12751744f;               // (1/sqrt(128)) * log2(e)
    const int qg = qw0 + lr;
    const int nt = (q0 >> 6) + 2;
    const int srcA = lr + ((lg & 1) << 5);      // P-exchange source lanes
    const int srcB = srcA + 16;
    const bool hiSel = (lg >= 2);

    // tile body; CAUSAL selected at compile time (wave-uniform call sites)
    auto TILE = [&](int t, int buf, auto CAUSAL_c) {
        constexpr bool CAUSAL = decltype(CAUSAL_c)::value;
        const int kv0 = t << 6;
        const unsigned short* kb = &lK[buf][0];
        const unsigned short* vb = &lVt[buf][0];

        // S^T = K @ Q^T : lane holds q = lr, kv rows = t2*16 + lg*4 + r
        f32x4 st[4];
        #pragma unroll
        for (int t2 = 0; t2 < 4; ++t2) st[t2] = (f32x4){0.f, 0.f, 0.f, 0.f};
        __builtin_amdgcn_s_setprio(1);
        #pragma unroll
        for (int t2 = 0; t2 < 4; ++t2) {
            const int krow = t2 * 16 + lr;
            #pragma unroll
            for (int ds = 0; ds < 4; ++ds) {
                const int ch = ds * 4 + lg;
                short8 kf = *(const short8*)&kb[krow * 128 + ((ch ^ (krow & 7)) << 3)];
                st[t2] = __builtin_amdgcn_mfma_f32_16x16x32_bf16(kf, qf[ds], st[t2], 0, 0, 0);
            }
        }
        __builtin_amdgcn_s_setprio(0);

        float sv[4][4];
        float rmax;
        if constexpr (CAUSAL) {
            const int* pm = &lPmB[buf][0];
            #pragma unroll
            for (int t2 = 0; t2 < 4; ++t2)
                #pragma unroll
                for (int r = 0; r < 4; ++r) {
                    int kvl = t2 * 16 + lg * 4 + r;
                    bool ok = ((kv0 + kvl) <= qg) && (pm[kvl] != 0);
                    sv[t2][r] = ok ? st[t2][r] * CS : -1.0e30f;
                }
            rmax = sv[0][0];
            #pragma unroll
            for (int t2 = 0; t2 < 4; ++t2)
                #pragma unroll
                for (int r = 0; r < 4; ++r) rmax = fmaxf(rmax, sv[t2][r]);
            rmax = fmaxf(rmax, __shfl_xor(rmax, 16, 64));
            rmax = fmaxf(rmax, __shfl_xor(rmax, 32, 64));
        } else {
            rmax = st[0][0];
            #pragma unroll
            for (int t2 = 0; t2 < 4; ++t2)
                #pragma unroll
                for (int r = 0; r < 4; ++r) rmax = fmaxf(rmax, st[t2][r]);
            rmax = fmaxf(rmax, __shfl_xor(rmax, 16, 64));
            rmax = fmaxf(rmax, __shfl_xor(rmax, 32, 64));
            rmax *= CS;   // scale once after reduction
        }

        // T13 defer-max: skip rescale when tile max grew < 8 (exp2 headroom 256)
        if (!__all(rmax - mrow <= 8.0f)) {
            float mn = fmaxf(mrow, rmax);
            float alpha = exp2f(mrow - mn);
            mrow = mn;
            lrow *= alpha;
            #pragma unroll
            for (int n = 0; n < 8; n++)
                #pragma unroll
                for (int r = 0; r < 4; r++) acc[n][r] *= alpha;
        }

        float p[4][4]; float psum = 0.f;
        if constexpr (CAUSAL) {
            #pragma unroll
            for (int t2 = 0; t2 < 4; ++t2)
                #pragma unroll
                for (int r = 0; r < 4; ++r) {
                    float e = exp2f(sv[t2][r] - mrow);
                    p[t2][r] = (sv[t2][r] > -5.0e29f) ? e : 0.f;
                    psum += p[t2][r];
                }
        } else {
            if (lPmOk[buf]) {
                #pragma unroll
                for (int t2 = 0; t2 < 4; ++t2)
                    #pragma unroll
                    for (int r = 0; r < 4; ++r) {
                        p[t2][r] = exp2f(fmaf(st[t2][r], CS, -mrow));
                        psum += p[t2][r];
                    }
            } else {
                const int* pm = &lPmB[buf][0];
                #pragma unroll
                for (int t2 = 0; t2 < 4; ++t2)
                    #pragma unroll
                    for (int r = 0; r < 4; ++r) {
                        int kvl = t2 * 16 + lg * 4 + r;
                        float e = exp2f(fmaf(st[t2][r], CS, -mrow));
                        p[t2][r] = (pm[kvl] != 0) ? e : 0.f;
                        psum += p[t2][r];
                    }
            }
        }
        psum += __shfl_xor(psum, 16, 64);
        psum += __shfl_xor(psum, 32, 64);
        lrow += psum;

        // pack P to bf16 pairs (hw cvt_pk): pk[t2][pp] = bf16(p[2pp]) | bf16(p[2pp+1])<<16
        uint32_t pk[4][2];
        #pragma unroll
        for (int t2 = 0; t2 < 4; ++t2)
            #pragma unroll
            for (int pp = 0; pp < 2; ++pp)
                pk[t2][pp] = cvt_pk_bf16(p[t2][2 * pp], p[t2][2 * pp + 1]);

        // exchange to B-fragments of P^T
        union U { uint32_t u[4]; short8 s; } pa0, pa1;
        {
            uint32_t l0 = (uint32_t)__shfl((int)pk[0][0], srcA, 64), h0 = (uint32_t)__shfl((int)pk[1][0], srcA, 64);
            uint32_t l1 = (uint32_t)__shfl((int)pk[0][1], srcA, 64), h1 = (uint32_t)__shfl((int)pk[1][1], srcA, 64);
            uint32_t l2 = (uint32_t)__shfl((int)pk[0][0], srcB, 64), h2 = (uint32_t)__shfl((int)pk[1][0], srcB, 64);
            uint32_t l3 = (uint32_t)__shfl((int)pk[0][1], srcB, 64), h3 = (uint32_t)__shfl((int)pk[1][1], srcB, 64);
            pa0.u[0] = hiSel ? h0 : l0; pa0.u[1] = hiSel ? h1 : l1;
            pa0.u[2] = hiSel ? h2 : l2; pa0.u[3] = hiSel ? h3 : l3;
        }
        {
            uint32_t l0 = (uint32_t)__shfl((int)pk[2][0], srcA, 64), h0 = (uint32_t)__shfl((int)pk[3][0], srcA, 64);
            uint32_t l1 = (uint32_t)__shfl((int)pk[2][1], srcA, 64), h1 = (uint32_t)__shfl((int)pk[3][1], srcA, 64);
            uint32_t l2 = (uint32_t)__shfl((int)pk[2][0], srcB, 64), h2 = (uint32_t)__shfl((int)pk[3][0], srcB, 64);
            uint32_t l3 = (uint32_t)__shfl((int)pk[2][1], srcB, 64), h3 = (uint32_t)__shfl((int)pk[3][1], srcB, 64);
            pa1.u[0] = hiSel ? h0 : l0; pa1.u[1] = hiSel ? h1 : l1;
            pa1.u[2] = hiSel ? h2 : l2; pa1.u[3] = hiSel ? h3 : l3;
        }

        // PV: ctx^T += V^T @ P^T
        __builtin_amdgcn_s_setprio(1);
        #pragma unroll
        for (int n = 0; n < 8; n++) {
            const int vrow = n * 16 + lr;
            short8 a0 = *(const short8*)&vb[vrow * 64 + ((lg ^ (vrow & 7)) << 3)];
            acc[n] = __builtin_amdgcn_mfma_f32_16x16x32_bf16(a0, pa0.s, acc[n], 0, 0, 0);
            short8 a1 = *(const short8*)&vb[vrow * 64 + (((4 + lg) ^ (vrow & 7)) << 3)];
            acc[n] = __builtin_amdgcn_mfma_f32_16x16x32_bf16(a1, pa1.s, acc[n], 0, 0, 0);
        }
        __builtin_amdgcn_s_setprio(0);
    };

    STAGE(0, 0);
    __syncthreads();
    int cur = 0;

    for (int t = 0; t < nt; ++t) {
        if (t + 1 < nt) STAGE(t + 1, cur ^ 1);   // issue-early: latency hides under compute
        const int kv0 = t << 6;
        if (kv0 <= qw0 + 15) {                   // wave-uniform: skip fully-masked tiles
            if (kv0 + 63 > qw0) TILE(t, cur, std::integral_constant<bool, true>{});
            else                TILE(t, cur, std::integral_constant<bool, false>{});
        }
        __syncthreads();   // drains vmcnt for t+1 stage (overlapped with this tile's compute)
        cur ^= 1;
    }

    // epilogue: ctx[q][hd] = acc^T / lrow ; 8B stores (4 consecutive hd per lane)
    float inv = 1.0f / lrow;
    #pragma unroll
    for (int n = 0; n < 8; n++) {
        short4v o;
        #pragma unroll
        for (int r = 0; r < 4; r++) o[r] = (short)bf16_rne(acc[n][r] * inv);
        *(short4v*)&CTX[hoff + (size_t)qg * Dv + n * 16 + lg * 4] = o;
    }
}

// ---------------- launcher ----------------
extern "C" void kernel_launch(void* const* d_in, const int* in_sizes, int n_in,
                              void* d_out, int out_size, void* d_ws, size_t ws_size,
                              hipStream_t stream) {
    const float* hs  = (const float*)d_in[0];
    const int*   am  = (const int*)d_in[1];
    const float* wq  = (const float*)d_in[2];
    const float* wk  = (const float*)d_in[3];
    const float* wv_ = (const float*)d_in[4];
    const float* wo  = (const float*)d_in[5];
    const float* bo  = (const float*)d_in[6];
    float* out = (float*)d_out;

    char* ws = (char*)d_ws;
    unsigned short* Xb  = (unsigned short*)ws;                               // 16 MiB: X bf16
    unsigned short* Wt  = (unsigned short*)(ws + (size_t)16 * 1024 * 1024);  // 32 MiB: 4x Wt bf16
    unsigned short* QKV = (unsigned short*)(ws + (size_t)48 * 1024 * 1024);  // 48 MiB: Q,K,VT bf16
    unsigned short* CTX = (unsigned short*)(ws + (size_t)96 * 1024 * 1024);  // 16 MiB: ctx bf16
    unsigned short* VT  = QKV + 2 * (size_t)Mv * Dv;                         // V stored transposed

    hipLaunchKernelGGL(cvt_x_kernel, dim3(Mv * Dv / 4 / 256), dim3(256), 0, stream, hs, Xb);
    hipLaunchKernelGGL(cvt_wt_kernel, dim3(32, 32, 4), dim3(256), 0, stream, wq, wk, wv_, wo, Wt);
    hipLaunchKernelGGL(gemm_bt_kernel<0>, dim3(32, 16, 3), dim3(256), 0, stream,
                       Xb, Wt, QKV, VT, (float*)nullptr, (const float*)nullptr);
    hipLaunchKernelGGL(attn_kernel, dim3(512), dim3(512), 0, stream,
                       QKV, QKV + (size_t)Mv * Dv, VT, am, CTX);
    hipLaunchKernelGGL(gemm_bt_kernel<1>, dim3(32, 16, 1), dim3(256), 0, stream,
                       CTX, Wt + 3 * (size_t)Dv * Dv, (unsigned short*)nullptr, (unsigned short*)nullptr, out, bo);
}

// Round 5
// 243.110 us; speedup vs baseline: 2.4729x; 1.0702x over previous
//
#include <hip/hip_runtime.h>
#include <hip/hip_bf16.h>
#include <stdint.h>

// Problem constants (FlaxGPTNeoSelfAttention): B=2, S=2048, D=2048, H=16, HD=128
#define Bv 2
#define Sv 2048
#define Dv 2048
#define Hv 16
#define HDv 128
#define Mv (Bv*Sv)   // 4096 rows for the projection GEMMs

typedef __attribute__((ext_vector_type(8))) short short8;
typedef __attribute__((ext_vector_type(4))) short short4v;
typedef __attribute__((ext_vector_type(4))) float f32x4;

__device__ __forceinline__ unsigned short bf16_rne(float f) {
    union { float f; uint32_t u; } c; c.f = f;
    uint32_t u = c.u;
    u += 0x7fffu + ((u >> 16) & 1u);   // round-to-nearest-even
    return (unsigned short)(u >> 16);
}

__device__ __forceinline__ uint32_t cvt_pk_bf16(float lo, float hi) {
    uint32_t r;
    asm("v_cvt_pk_bf16_f32 %0, %1, %2" : "=v"(r) : "v"(lo), "v"(hi));
    return r;
}

__device__ __forceinline__ void gload16(const void* g, void* l) {
    // async global->LDS, 16B per lane; LDS dest = wave-uniform base + lane*16
    __builtin_amdgcn_global_load_lds((const __attribute__((address_space(1))) void*)g,
                                     (__attribute__((address_space(3))) void*)l, 16, 0, 0);
}

// ---------------- kernel 1: hidden_states fp32 -> bf16 ----------------
__global__ void cvt_x_kernel(const float* __restrict__ x, unsigned short* __restrict__ xb) {
    int i = (blockIdx.x * 256 + threadIdx.x) * 4;
    float4 v = *(const float4*)(x + i);
    short4v o;
    o[0] = (short)bf16_rne(v.x);
    o[1] = (short)bf16_rne(v.y);
    o[2] = (short)bf16_rne(v.z);
    o[3] = (short)bf16_rne(v.w);
    *(short4v*)(xb + i) = o;
}

// ---------------- kernel 2: weights fp32 -> bf16, transposed Wt[n][k] ----------------
__global__ void cvt_wt_kernel(const float* __restrict__ w0, const float* __restrict__ w1,
                              const float* __restrict__ w2, const float* __restrict__ w3,
                              unsigned short* __restrict__ wt) {
    __shared__ unsigned short t[64][65];
    int z = blockIdx.z;
    const float* w = (z == 0) ? w0 : (z == 1) ? w1 : (z == 2) ? w2 : w3;
    unsigned short* o = wt + (size_t)z * Dv * Dv;
    int k0 = blockIdx.x * 64, n0 = blockIdx.y * 64;
    for (int i = threadIdx.x; i < 4096; i += 256) {
        int r = i >> 6, c = i & 63;
        t[r][c] = bf16_rne(w[(size_t)(k0 + r) * Dv + n0 + c]);
    }
    __syncthreads();
    for (int i = threadIdx.x; i < 4096; i += 256) {
        int r = i >> 6, c = i & 63;
        o[(size_t)(n0 + r) * Dv + k0 + c] = t[c][r];
    }
}

// ---------------- kernel 2b: V (bf16 [4096][2048]) -> VT per batch ([b*2048+c][s]) ----------------
__global__ void vt_kernel(const unsigned short* __restrict__ V, unsigned short* __restrict__ VT) {
    __shared__ unsigned short t[64 * 64];   // XOR chunk-swizzled 64x64 tile
    const int tid = threadIdx.x;
    const int b = blockIdx.z;
    const int s0 = blockIdx.x * 64, c0 = blockIdx.y * 64;
    const unsigned short* Vb = V + (size_t)b * Sv * Dv;
    unsigned short* VTb = VT + (size_t)b * Dv * Sv;
    #pragma unroll
    for (int ii = 0; ii < 2; ++ii) {
        int i = tid + ii * 256;
        int r = i >> 3, ch = i & 7;            // row in tile, 8-short chunk
        short8 v = *(const short8*)&Vb[(size_t)(s0 + r) * Dv + c0 + ch * 8];
        *(short8*)&t[r * 64 + ((ch ^ (r & 7)) << 3)] = v;
    }
    __syncthreads();
    #pragma unroll
    for (int ii = 0; ii < 2; ++ii) {
        int o = tid + ii * 256;
        int orow = o >> 3, och = o & 7;        // output row = c index, chunk along s
        short8 v;
        #pragma unroll
        for (int j = 0; j < 8; ++j) {
            int r = och * 8 + j;               // source tile row (s index)
            int c = orow;                      // source tile col (c index)
            v[j] = (short)t[r * 64 + ((((c >> 3) ^ (r & 7)) << 3) | (c & 7))];
        }
        *(short8*)&VTb[(size_t)(c0 + orow) * Sv + s0 + och * 8] = v;
    }
}

// ---------------- kernel 3/5: pipelined GEMM  C[M][Ng] = A[M][K] @ Wt[Ng][K]^T ----------------
// 128x256 tile, BK=64, 8 waves (2M x 4N), 3-buffer LDS ring, counted vmcnt(6),
// raw s_barrier (no vmcnt0 drain), XOR chunk-swizzled staging/reads.
// FOUT=0: bf16 store to CbBase with z = n_global>>11 split (QKV fused N=6144).
// FOUT=1: fp32 store to Cf with +bias (N=2048).
template<int FOUT>
__global__ __launch_bounds__(512, 2) void gemm8_kernel(
    const unsigned short* __restrict__ A,
    const unsigned short* __restrict__ WtBase,
    unsigned short* __restrict__ CbBase,
    float* __restrict__ Cf,
    const float* __restrict__ bias,
    int per_xcd_n)
{
    extern __shared__ unsigned short lds[];    // 3 bufs x (A 8192 + B 16384) shorts = 144 KiB
    const int tid = threadIdx.x;
    const int wv = tid >> 6, ln = tid & 63;
    const int lr = ln & 15, lg = ln >> 4;
    const int wm = wv >> 2, wn = wv & 3;

    // XCD-major swizzle: grid = 8 * per_xcd_n * 32 blocks; W-panel resident per XCD
    const int bid = blockIdx.x;
    const int xcd = bid & 7, idx = bid >> 3;
    const int n_idx = xcd * per_xcd_n + (idx >> 5);
    const int m_idx = idx & 31;
    const int m0 = m_idx * 128;
    const int n0g = n_idx * 256;
    const int NT = Dv / 64;                    // 32 K-tiles

    // staging source addresses (pre-swizzled global, linear LDS dest)
    const int srow = ln >> 3;                              // 0..7
    const int swz = ((ln & 7) ^ srow) << 3;                // swizzled k-chunk (shorts)
    const unsigned short* Ab = A      + (size_t)(m0  + wv * 8 + srow) * Dv + swz;
    const unsigned short* Bb = WtBase + (size_t)(n0g + wv * 8 + srow) * Dv + swz;

    auto STAGE_A = [&](int t, int d) {
        const unsigned short* g = Ab + t * 64;
        #pragma unroll
        for (int j = 0; j < 2; ++j)
            gload16(g + (size_t)(j * 64) * Dv, &lds[d * 24576 + (j * 64 + wv * 8) * 64]);
    };
    auto STAGE_B = [&](int t, int d) {
        const unsigned short* g = Bb + t * 64;
        #pragma unroll
        for (int j = 0; j < 4; ++j)
            gload16(g + (size_t)(j * 64) * Dv, &lds[d * 24576 + 8192 + (j * 64 + wv * 8) * 64]);
    };

    // fragment read offsets (shorts): chunk = (ks*4+lg) ^ (lr&7)
    const int aro = (wm * 64 + lr) * 64;       // + mi*1024
    const int bro = (wn * 64 + lr) * 64;       // + ni*1024
    const int ach0 = ((lg ^ (lr & 7)) << 3);
    const int ach1 = (((4 + lg) ^ (lr & 7)) << 3);

    f32x4 acc[4][4];
    #pragma unroll
    for (int mi = 0; mi < 4; mi++)
        #pragma unroll
        for (int ni = 0; ni < 4; ni++)
            acc[mi][ni] = (f32x4){0.f, 0.f, 0.f, 0.f};

    // prologue: T0 -> buf0, T1 -> buf1; wait T0 (vmcnt(6) leaves T1's 6 loads in flight)
    STAGE_A(0, 0); STAGE_B(0, 0);
    STAGE_A(1, 1); STAGE_B(1, 1);
    asm volatile("s_waitcnt vmcnt(6)" ::: "memory");
    asm volatile("s_barrier" ::: "memory");

    for (int t = 0; t < NT; ++t) {
        const int d = t % 3, d2 = (t + 2) % 3;
        const unsigned short* la = &lds[d * 24576];
        const unsigned short* lb = &lds[d * 24576 + 8192];

        // ---- phase A: read all A frags + B n0,n1; stage A(t+2); MFMA (n0,n1)
        short8 af[4][2], bf0[2][2];
        #pragma unroll
        for (int mi = 0; mi < 4; mi++) {
            af[mi][0] = *(const short8*)&la[aro + mi * 1024 + ach0];
            af[mi][1] = *(const short8*)&la[aro + mi * 1024 + ach1];
        }
        #pragma unroll
        for (int ni = 0; ni < 2; ni++) {
            bf0[ni][0] = *(const short8*)&lb[bro + ni * 1024 + ach0];
            bf0[ni][1] = *(const short8*)&lb[bro + ni * 1024 + ach1];
        }
        if (t + 2 < NT) STAGE_A(t + 2, d2);
        asm volatile("s_barrier" ::: "memory");
        __builtin_amdgcn_s_setprio(1);
        #pragma unroll
        for (int mi = 0; mi < 4; mi++)
            #pragma unroll
            for (int ni = 0; ni < 2; ni++) {
                acc[mi][ni] = __builtin_amdgcn_mfma_f32_16x16x32_bf16(af[mi][0], bf0[ni][0], acc[mi][ni], 0, 0, 0);
                acc[mi][ni] = __builtin_amdgcn_mfma_f32_16x16x32_bf16(af[mi][1], bf0[ni][1], acc[mi][ni], 0, 0, 0);
            }
        __builtin_amdgcn_s_setprio(0);

        // ---- phase B: read B n2,n3; stage B(t+2); vmcnt(6); MFMA (n2,n3)
        short8 bf1[2][2];
        #pragma unroll
        for (int ni = 0; ni < 2; ni++) {
            bf1[ni][0] = *(const short8*)&lb[bro + (ni + 2) * 1024 + ach0];
            bf1[ni][1] = *(const short8*)&lb[bro + (ni + 2) * 1024 + ach1];
        }
        if (t + 2 < NT) STAGE_B(t + 2, d2);
        asm volatile("s_waitcnt vmcnt(6)" ::: "memory");
        asm volatile("s_barrier" ::: "memory");
        __builtin_amdgcn_s_setprio(1);
        #pragma unroll
        for (int mi = 0; mi < 4; mi++)
            #pragma unroll
            for (int ni = 0; ni < 2; ni++) {
                acc[mi][ni + 2] = __builtin_amdgcn_mfma_f32_16x16x32_bf16(af[mi][0], bf1[ni][0], acc[mi][ni + 2], 0, 0, 0);
                acc[mi][ni + 2] = __builtin_amdgcn_mfma_f32_16x16x32_bf16(af[mi][1], bf1[ni][1], acc[mi][ni + 2], 0, 0, 0);
            }
        __builtin_amdgcn_s_setprio(0);
    }

    // ---- epilogue: C layout row=(lg*4+r)+mi*16, col=lr+ni*16 within wave tile
    if (FOUT) {
        #pragma unroll
        for (int mi = 0; mi < 4; mi++)
            #pragma unroll
            for (int ni = 0; ni < 4; ni++) {
                int row = m0 + wm * 64 + mi * 16 + lg * 4;
                int col = n0g + wn * 64 + ni * 16 + lr;
                float bv = bias[col];
                #pragma unroll
                for (int r = 0; r < 4; r++)
                    Cf[(size_t)(row + r) * Dv + col] = acc[mi][ni][r] + bv;
            }
    } else {
        const int z = n0g >> 11;
        unsigned short* Cz = CbBase + (size_t)z * Mv * Dv;
        const int ncl = (n0g & 2047) + wn * 64;
        #pragma unroll
        for (int mi = 0; mi < 4; mi++)
            #pragma unroll
            for (int ni = 0; ni < 4; ni++) {
                int row = m0 + wm * 64 + mi * 16 + lg * 4;
                int col = ncl + ni * 16 + lr;
                #pragma unroll
                for (int r = 0; r < 4; r++)
                    Cz[(size_t)(row + r) * Dv + col] = bf16_rne(acc[mi][ni][r]);
            }
    }
}

// ---------------- kernel 4: causal flash attention ----------------
// 8 waves (512 thr), 128 q rows/block (16/wave), KVBLK=64, double-buffered LDS,
// swapped QK^T, in-reg softmax, causal work only on diagonal tiles.
__global__ __launch_bounds__(512) void attn_kernel(
    const unsigned short* __restrict__ Q, const unsigned short* __restrict__ K,
    const unsigned short* __restrict__ VT, const int* __restrict__ pmask,
    unsigned short* __restrict__ CTX)
{
    __shared__ unsigned short lK[2][64 * 128];    // K tiles, chunk-swizzled (ch^(row&7))
    __shared__ unsigned short lVt[2][128 * 64];   // V^T tiles, chunk-swizzled (ch^(row&7))
    __shared__ int lPmB[2][64];
    __shared__ int lPmOk[2];

    const int tid = threadIdx.x, wv = tid >> 6, ln = tid & 63;
    const int lr = ln & 15, lg = ln >> 4;
    const int L = blockIdx.x;
    const int bh = (L & 7) * 4 + ((L >> 3) & 3);
    const int b = bh >> 4, h = bh & 15;
    const int v = L >> 5;                          // 0..15
    const int qidx = (v < 8) ? (15 - v) : (v - 8);
    const int q0 = qidx * 128;
    const int qw0 = q0 + wv * 16;
    const size_t hoff  = (size_t)b * Sv * Dv + (size_t)h * HDv;
    const size_t vtoff = ((size_t)b * Dv + (size_t)h * HDv) * Sv;

    short8 qf[4];
    #pragma unroll
    for (int ds = 0; ds < 4; ds++)
        qf[ds] = *(const short8*)&Q[hoff + (size_t)(qw0 + lr) * Dv + ds * 32 + lg * 8];

    size_t koff[2], voff[2];
    #pragma unroll
    for (int ii = 0; ii < 2; ++ii) {
        int slot = ii * 512 + wv * 64 + ln;
        int krow = slot >> 4, kch = slot & 15;            // K: 64 rows x 16 chunks
        koff[ii] = hoff + (size_t)krow * Dv + ((kch ^ (krow & 7)) << 3);
        int vrow = slot >> 3, vch = slot & 7;             // VT: 128 rows x 8 chunks
        voff[ii] = vtoff + (size_t)vrow * Sv + ((vch ^ (vrow & 7)) << 3);
    }

    auto STAGE = [&](int t, int buf) {
        const size_t kadd = (size_t)(t << 6) * Dv;
        const int vadd = t << 6;
        unsigned short* kb = &lK[buf][0];
        unsigned short* vb = &lVt[buf][0];
        #pragma unroll
        for (int ii = 0; ii < 2; ++ii) {
            gload16(K + koff[ii] + kadd, kb + (ii * 512 + wv * 64) * 8);
            gload16(VT + voff[ii] + vadd, vb + (ii * 512 + wv * 64) * 8);
        }
        if (wv == 0) {
            int pmv = pmask[b * Sv + (t << 6) + ln];
            lPmB[buf][ln] = pmv;
            unsigned long long bal = __ballot(pmv != 0);
            if (ln == 0) lPmOk[buf] = (bal == ~0ull) ? 1 : 0;
        }
    };

    f32x4 acc[8];
    #pragma unroll
    for (int n = 0; n < 8; n++) acc[n] = (f32x4){0.f, 0.f, 0.f, 0.f};
    float mrow = -3.0e38f, lrow = 0.f;
    const float CS = 0.12751744f;               // (1/sqrt(128)) * log2(e)
    const int qg = qw0 + lr;
    const int nt = (q0 >> 6) + 2;
    const int srcA = lr + ((lg & 1) << 5);
    const int srcB = srcA + 16;
    const bool hiSel = (lg >= 2);

    auto TILE = [&](int t, int buf, auto CAUSAL_c) {
        constexpr bool CAUSAL = decltype(CAUSAL_c)::value;
        const int kv0 = t << 6;
        const unsigned short* kb = &lK[buf][0];
        const unsigned short* vb = &lVt[buf][0];

        f32x4 st[4];
        #pragma unroll
        for (int t2 = 0; t2 < 4; ++t2) st[t2] = (f32x4){0.f, 0.f, 0.f, 0.f};
        __builtin_amdgcn_s_setprio(1);
        #pragma unroll
        for (int t2 = 0; t2 < 4; ++t2) {
            const int krow = t2 * 16 + lr;
            #pragma unroll
            for (int ds = 0; ds < 4; ++ds) {
                const int ch = ds * 4 + lg;
                short8 kf = *(const short8*)&kb[krow * 128 + ((ch ^ (krow & 7)) << 3)];
                st[t2] = __builtin_amdgcn_mfma_f32_16x16x32_bf16(kf, qf[ds], st[t2], 0, 0, 0);
            }
        }
        __builtin_amdgcn_s_setprio(0);

        float sv[4][4];
        float rmax;
        if constexpr (CAUSAL) {
            const int* pm = &lPmB[buf][0];
            #pragma unroll
            for (int t2 = 0; t2 < 4; ++t2)
                #pragma unroll
                for (int r = 0; r < 4; ++r) {
                    int kvl = t2 * 16 + lg * 4 + r;
                    bool ok = ((kv0 + kvl) <= qg) && (pm[kvl] != 0);
                    sv[t2][r] = ok ? st[t2][r] * CS : -1.0e30f;
                }
            rmax = sv[0][0];
            #pragma unroll
            for (int t2 = 0; t2 < 4; ++t2)
                #pragma unroll
                for (int r = 0; r < 4; ++r) rmax = fmaxf(rmax, sv[t2][r]);
            rmax = fmaxf(rmax, __shfl_xor(rmax, 16, 64));
            rmax = fmaxf(rmax, __shfl_xor(rmax, 32, 64));
        } else {
            rmax = st[0][0];
            #pragma unroll
            for (int t2 = 0; t2 < 4; ++t2)
                #pragma unroll
                for (int r = 0; r < 4; ++r) rmax = fmaxf(rmax, st[t2][r]);
            rmax = fmaxf(rmax, __shfl_xor(rmax, 16, 64));
            rmax = fmaxf(rmax, __shfl_xor(rmax, 32, 64));
            rmax *= CS;
        }

        if (!__all(rmax - mrow <= 8.0f)) {
            float mn = fmaxf(mrow, rmax);
            float alpha = exp2f(mrow - mn);
            mrow = mn;
            lrow *= alpha;
            #pragma unroll
            for (int n = 0; n < 8; n++)
                #pragma unroll
                for (int r = 0; r < 4; r++) acc[n][r] *= alpha;
        }

        float p[4][4]; float psum = 0.f;
        if constexpr (CAUSAL) {
            #pragma unroll
            for (int t2 = 0; t2 < 4; ++t2)
                #pragma unroll
                for (int r = 0; r < 4; ++r) {
                    float e = exp2f(sv[t2][r] - mrow);
                    p[t2][r] = (sv[t2][r] > -5.0e29f) ? e : 0.f;
                    psum += p[t2][r];
                }
        } else {
            if (lPmOk[buf]) {
                #pragma unroll
                for (int t2 = 0; t2 < 4; ++t2)
                    #pragma unroll
                    for (int r = 0; r < 4; ++r) {
                        p[t2][r] = exp2f(fmaf(st[t2][r], CS, -mrow));
                        psum += p[t2][r];
                    }
            } else {
                const int* pm = &lPmB[buf][0];
                #pragma unroll
                for (int t2 = 0; t2 < 4; ++t2)
                    #pragma unroll
                    for (int r = 0; r < 4; ++r) {
                        int kvl = t2 * 16 + lg * 4 + r;
                        float e = exp2f(fmaf(st[t2][r], CS, -mrow));
                        p[t2][r] = (pm[kvl] != 0) ? e : 0.f;
                        psum += p[t2][r];
                    }
            }
        }
        psum += __shfl_xor(psum, 16, 64);
        psum += __shfl_xor(psum, 32, 64);
        lrow += psum;

        uint32_t pk[4][2];
        #pragma unroll
        for (int t2 = 0; t2 < 4; ++t2)
            #pragma unroll
            for (int pp = 0; pp < 2; ++pp)
                pk[t2][pp] = cvt_pk_bf16(p[t2][2 * pp], p[t2][2 * pp + 1]);

        union U { uint32_t u[4]; short8 s; } pa0, pa1;
        {
            uint32_t l0 = (uint32_t)__shfl((int)pk[0][0], srcA, 64), h0 = (uint32_t)__shfl((int)pk[1][0], srcA, 64);
            uint32_t l1 = (uint32_t)__shfl((int)pk[0][1], srcA, 64), h1 = (uint32_t)__shfl((int)pk[1][1], srcA, 64);
            uint32_t l2 = (uint32_t)__shfl((int)pk[0][0], srcB, 64), h2 = (uint32_t)__shfl((int)pk[1][0], srcB, 64);
            uint32_t l3 = (uint32_t)__shfl((int)pk[0][1], srcB, 64), h3 = (uint32_t)__shfl((int)pk[1][1], srcB, 64);
            pa0.u[0] = hiSel ? h0 : l0; pa0.u[1] = hiSel ? h1 : l1;
            pa0.u[2] = hiSel ? h2 : l2; pa0.u[3] = hiSel ? h3 : l3;
        }
        {
            uint32_t l0 = (uint32_t)__shfl((int)pk[2][0], srcA, 64), h0 = (uint32_t)__shfl((int)pk[3][0], srcA, 64);
            uint32_t l1 = (uint32_t)__shfl((int)pk[2][1], srcA, 64), h1 = (uint32_t)__shfl((int)pk[3][1], srcA, 64);
            uint32_t l2 = (uint32_t)__shfl((int)pk[2][0], srcB, 64), h2 = (uint32_t)__shfl((int)pk[3][0], srcB, 64);
            uint32_t l3 = (uint32_t)__shfl((int)pk[2][1], srcB, 64), h3 = (uint32_t)__shfl((int)pk[3][1], srcB, 64);
            pa1.u[0] = hiSel ? h0 : l0; pa1.u[1] = hiSel ? h1 : l1;
            pa1.u[2] = hiSel ? h2 : l2; pa1.u[3] = hiSel ? h3 : l3;
        }

        __builtin_amdgcn_s_setprio(1);
        #pragma unroll
        for (int n = 0; n < 8; n++) {
            const int vrow = n * 16 + lr;
            short8 a0 = *(const short8*)&vb[vrow * 64 + ((lg ^ (vrow & 7)) << 3)];
            acc[n] = __builtin_amdgcn_mfma_f32_16x16x32_bf16(a0, pa0.s, acc[n], 0, 0, 0);
            short8 a1 = *(const short8*)&vb[vrow * 64 + (((4 + lg) ^ (vrow & 7)) << 3)];
            acc[n] = __builtin_amdgcn_mfma_f32_16x16x32_bf16(a1, pa1.s, acc[n], 0, 0, 0);
        }
        __builtin_amdgcn_s_setprio(0);
    };

    STAGE(0, 0);
    __syncthreads();
    int cur = 0;

    for (int t = 0; t < nt; ++t) {
        if (t + 1 < nt) STAGE(t + 1, cur ^ 1);
        const int kv0 = t << 6;
        if (kv0 <= qw0 + 15) {
            if (kv0 + 63 > qw0) TILE(t, cur, std::integral_constant<bool, true>{});
            else                TILE(t, cur, std::integral_constant<bool, false>{});
        }
        __syncthreads();
        cur ^= 1;
    }

    float inv = 1.0f / lrow;
    #pragma unroll
    for (int n = 0; n < 8; n++) {
        short4v o;
        #pragma unroll
        for (int r = 0; r < 4; r++) o[r] = (short)bf16_rne(acc[n][r] * inv);
        *(short4v*)&CTX[hoff + (size_t)qg * Dv + n * 16 + lg * 4] = o;
    }
}

// ---------------- launcher ----------------
extern "C" void kernel_launch(void* const* d_in, const int* in_sizes, int n_in,
                              void* d_out, int out_size, void* d_ws, size_t ws_size,
                              hipStream_t stream) {
    const float* hs  = (const float*)d_in[0];
    const int*   am  = (const int*)d_in[1];
    const float* wq  = (const float*)d_in[2];
    const float* wk  = (const float*)d_in[3];
    const float* wv_ = (const float*)d_in[4];
    const float* wo  = (const float*)d_in[5];
    const float* bo  = (const float*)d_in[6];
    float* out = (float*)d_out;

    char* ws = (char*)d_ws;
    unsigned short* Xb  = (unsigned short*)ws;                               // 16 MiB: X bf16; later VT
    unsigned short* Wt  = (unsigned short*)(ws + (size_t)16 * 1024 * 1024);  // 32 MiB: 4x Wt bf16
    unsigned short* QKV = (unsigned short*)(ws + (size_t)48 * 1024 * 1024);  // 48 MiB: Q,K,V bf16
    unsigned short* CTX = (unsigned short*)(ws + (size_t)96 * 1024 * 1024);  // 16 MiB: ctx bf16
    unsigned short* VT  = Xb;                                                // alias (Xb dead after QKV GEMM)

    const int LDSB = 3 * 24576 * 2;   // 147456 B dynamic LDS
    static bool attrSet = false;
    if (!attrSet) {
        hipFuncSetAttribute((const void*)gemm8_kernel<0>, hipFuncAttributeMaxDynamicSharedMemorySize, LDSB);
        hipFuncSetAttribute((const void*)gemm8_kernel<1>, hipFuncAttributeMaxDynamicSharedMemorySize, LDSB);
        attrSet = true;
    }

    hipLaunchKernelGGL(cvt_x_kernel, dim3(Mv * Dv / 4 / 256), dim3(256), 0, stream, hs, Xb);
    hipLaunchKernelGGL(cvt_wt_kernel, dim3(32, 32, 4), dim3(256), 0, stream, wq, wk, wv_, wo, Wt);
    // QKV fused: N_global = 6144 -> 24 n-blocks, 32 m-blocks, 768 blocks (3 exact CU rounds)
    hipLaunchKernelGGL(gemm8_kernel<0>, dim3(768), dim3(512), LDSB, stream,
                       Xb, Wt, QKV, (float*)nullptr, (const float*)nullptr, 3);
    hipLaunchKernelGGL(vt_kernel, dim3(32, 32, 2), dim3(256), 0, stream,
                       QKV + 2 * (size_t)Mv * Dv, VT);
    hipLaunchKernelGGL(attn_kernel, dim3(512), dim3(512), 0, stream,
                       QKV, QKV + (size_t)Mv * Dv, VT, am, CTX);
    // out-proj: N=2048 -> 8 n-blocks, 256 blocks (1 exact CU round)
    hipLaunchKernelGGL(gemm8_kernel<1>, dim3(256), dim3(512), LDSB, stream,
                       CTX, Wt + 3 * (size_t)Dv * Dv, (unsigned short*)nullptr, out, bo, 1);
}